// Round 1
// baseline (2478.950 us; speedup 1.0000x reference)
//
#include <hip/hip_runtime.h>
#include <math.h>

#define NG 1024  // NUM_GRAPHS

static inline int cdiv_i(long long a, int b) { return (int)((a + b - 1) / b); }

// ---- degree / dinv -------------------------------------------------------
__global__ void deg_count(const int* __restrict__ dst, int* __restrict__ deg, int E) {
    int t = blockIdx.x * blockDim.x + threadIdx.x;
    if (t < E) atomicAdd(&deg[dst[t]], 1);
}

// in-place: buf holds int counts, becomes float dinv = rsqrt(count + 1 self-loop)
__global__ void deg_to_dinv(float* __restrict__ buf, int N) {
    int t = blockIdx.x * blockDim.x + threadIdx.x;
    if (t < N) {
        int d = reinterpret_cast<const int*>(buf)[t];
        buf[t] = rsqrtf((float)(d + 1));
    }
}

// ---- per-layer fused GEMM ------------------------------------------------
// hs[i][f] = dinv[i] * sum_k inval(i,k) * W[k][f];  acc[i][f] = hs[i][f] (self loop)
// inval = PRE ? relu(dinv[i]*in[i][k] + preb[k]) : in[i][k]
template <int FIN, int FOUT, bool PRE>
__global__ void gemm_scale(const float* __restrict__ in, const float* __restrict__ dinv,
                           const float* __restrict__ preb, const float* __restrict__ W,
                           float* __restrict__ hs, float* __restrict__ acc, int N) {
    int t = blockIdx.x * blockDim.x + threadIdx.x;
    int i = t / FOUT, f = t % FOUT;
    if (i >= N) return;
    float di = dinv[i];
    float s = 0.f;
#pragma unroll 8
    for (int k = 0; k < FIN; ++k) {
        float v = in[i * FIN + k];
        if (PRE) v = fmaxf(di * v + preb[k], 0.f);
        s += v * W[k * FOUT + f];
    }
    s *= di;
    hs[i * FOUT + f] = s;
    acc[i * FOUT + f] = s;
}

// ---- edge scatter: acc[dst] += hs[src] -----------------------------------
template <int F>
__global__ void scatter_add(const int* __restrict__ src, const int* __restrict__ dst,
                            const float* __restrict__ hs, float* __restrict__ acc, int E) {
    const int C = F / 4;  // float4 chunks per row
    int t = blockIdx.x * blockDim.x + threadIdx.x;
    int e = t / C, c = t % C;
    if (e >= E) return;
    int s = src[e], d = dst[e];
    const float4 v = *reinterpret_cast<const float4*>(hs + (size_t)s * F + c * 4);
    float* p = acc + (size_t)d * F + c * 4;
    atomicAdd(p + 0, v.x);
    atomicAdd(p + 1, v.y);
    atomicAdd(p + 2, v.z);
    atomicAdd(p + 3, v.w);
}

// ---- layer-3 epilogue + segment-max pool ---------------------------------
// v = relu(dinv[i]*acc[i][f] + b[f]) >= 0, so float-as-uint atomicMax is valid (pooled 0-init)
__global__ void finish_pool(const float* __restrict__ acc, const float* __restrict__ dinv,
                            const float* __restrict__ b, const int* __restrict__ batch,
                            unsigned* __restrict__ pooled, int N) {
    int t = blockIdx.x * blockDim.x + threadIdx.x;
    int i = t >> 6, f = t & 63;
    if (i >= N) return;
    float v = fmaxf(dinv[i] * acc[t] + b[f], 0.f);
    atomicMax(&pooled[batch[i] * 64 + f], __float_as_uint(v));
}

// ---- MLP head: one block (256 thr) per graph -----------------------------
__global__ void head(const float* __restrict__ pooled, const float* __restrict__ w1,
                     const float* __restrict__ bb1, const float* __restrict__ w2,
                     const float* __restrict__ bb2, float* __restrict__ out) {
    __shared__ float p[64];
    __shared__ float z[256];
    int g = blockIdx.x, t = threadIdx.x;
    if (t < 64) p[t] = pooled[g * 64 + t];
    __syncthreads();
    float s = bb1[t];
#pragma unroll
    for (int k = 0; k < 64; ++k) s += p[k] * w1[k * 256 + t];
    z[t] = fmaxf(s, 0.f);
    __syncthreads();
    float s2 = bb2[t];
#pragma unroll 8
    for (int k = 0; k < 256; ++k) s2 += z[k] * w2[k * 256 + t];
    out[g * 256 + t] = 1.f / (1.f + expf(-s2));
}

extern "C" void kernel_launch(void* const* d_in, const int* in_sizes, int n_in,
                              void* d_out, int out_size, void* d_ws, size_t ws_size,
                              hipStream_t stream) {
    const float* x   = (const float*)d_in[0];
    const int* ei    = (const int*)d_in[1];
    const int* batch = (const int*)d_in[2];
    const float* W1  = (const float*)d_in[3];
    const float* b1  = (const float*)d_in[4];
    const float* W2  = (const float*)d_in[5];
    const float* b2  = (const float*)d_in[6];
    const float* W3  = (const float*)d_in[7];
    const float* b3  = (const float*)d_in[8];
    const float* L1w = (const float*)d_in[9];
    const float* L1b = (const float*)d_in[10];
    const float* L2w = (const float*)d_in[11];
    const float* L2b = (const float*)d_in[12];

    const int N = in_sizes[0] / 128;
    const int E = in_sizes[1] / 2;
    const int* srcp = ei;
    const int* dstp = ei + E;

    float* ws = (float*)d_ws;
    float* dinv = ws;                               // N floats (int deg alias first)
    float* hs   = ws + N;                           // N*64
    float* accA = hs + (size_t)N * 64;              // N*64
    float* accB = accA + (size_t)N * 64;            // N*64
    unsigned* pooled = (unsigned*)(accB + (size_t)N * 64);  // NG*64

    hipMemsetAsync(dinv, 0, (size_t)N * sizeof(int), stream);
    hipMemsetAsync(pooled, 0, (size_t)NG * 64 * sizeof(float), stream);

    deg_count<<<cdiv_i(E, 256), 256, 0, stream>>>(dstp, (int*)dinv, E);
    deg_to_dinv<<<cdiv_i(N, 256), 256, 0, stream>>>(dinv, N);

    // Layer 1: x[128] -> 16
    gemm_scale<128, 16, false><<<cdiv_i((long long)N * 16, 256), 256, 0, stream>>>(
        x, dinv, nullptr, W1, hs, accA, N);
    scatter_add<16><<<cdiv_i((long long)E * 4, 256), 256, 0, stream>>>(srcp, dstp, hs, accA, E);

    // Layer 2: 16 -> 32 (fused relu(dinv*acc1+b1) on input)
    gemm_scale<16, 32, true><<<cdiv_i((long long)N * 32, 256), 256, 0, stream>>>(
        accA, dinv, b1, W2, hs, accB, N);
    scatter_add<32><<<cdiv_i((long long)E * 8, 256), 256, 0, stream>>>(srcp, dstp, hs, accB, E);

    // Layer 3: 32 -> 64
    gemm_scale<32, 64, true><<<cdiv_i((long long)N * 64, 256), 256, 0, stream>>>(
        accB, dinv, b2, W3, hs, accA, N);
    scatter_add<64><<<cdiv_i((long long)E * 16, 256), 256, 0, stream>>>(srcp, dstp, hs, accA, E);

    // epilogue + pool + head
    finish_pool<<<cdiv_i((long long)N * 64, 256), 256, 0, stream>>>(accA, dinv, b3, batch, pooled, N);
    head<<<NG, 256, 0, stream>>>((const float*)pooled, L1w, L1b, L2w, L2b, (float*)d_out);
}

// Round 2
// 763.968 us; speedup vs baseline: 3.2448x; 3.2448x over previous
//
#include <hip/hip_runtime.h>
#include <math.h>

#define NG 1024  // NUM_GRAPHS

static inline int cdiv_i(long long a, int b) { return (int)((a + b - 1) / b); }

// ---- CSR build -----------------------------------------------------------
__global__ void deg_count(const int* __restrict__ dst, int* __restrict__ deg, int E) {
    int t = blockIdx.x * blockDim.x + threadIdx.x;
    if (t < E) atomicAdd(&deg[dst[t]], 1);
}

// one block of 1024 threads: exclusive scan of deg[N] -> rowptr[N+1]
__global__ void scan_deg(const int* __restrict__ deg, int* __restrict__ rowptr, int N) {
    __shared__ int sums[1024];
    int t = threadIdx.x;
    int chunk = (N + 1023) / 1024;
    int lo = t * chunk, hi = min(lo + chunk, N);
    if (lo > N) lo = N;
    int s = 0;
    for (int i = lo; i < hi; ++i) s += deg[i];
    sums[t] = s;
    __syncthreads();
    for (int off = 1; off < 1024; off <<= 1) {
        int v = (t >= off) ? sums[t - off] : 0;
        __syncthreads();
        sums[t] += v;
        __syncthreads();
    }
    int excl = (t == 0) ? 0 : sums[t - 1];
    for (int i = lo; i < hi; ++i) { rowptr[i] = excl; excl += deg[i]; }
    if (hi == N) rowptr[N] = excl;  // (benign same-value multi-write if trailing threads empty)
}

__global__ void deg_to_dinv(const int* __restrict__ deg, float* __restrict__ dinv, int N) {
    int t = blockIdx.x * blockDim.x + threadIdx.x;
    if (t < N) dinv[t] = rsqrtf((float)(deg[t] + 1));  // +1 self-loop
}

__global__ void fill_csr(const int* __restrict__ src, const int* __restrict__ dst,
                         const int* __restrict__ rowptr, int* __restrict__ cursor,
                         int* __restrict__ csr_src, int E) {
    int e = blockIdx.x * blockDim.x + threadIdx.x;
    if (e >= E) return;
    int d = dst[e];
    int pos = atomicAdd(&cursor[d], 1);
    csr_src[rowptr[d] + pos] = src[e];
}

// ---- per-layer fused GEMM ------------------------------------------------
// hs[i][f] = dinv[i] * sum_k inval(i,k) * W[k][f]
// inval = PRE ? relu(dinv[i]*in[i][k] + preb[k]) : in[i][k]
template <int FIN, int FOUT, bool PRE>
__global__ void gemm_scale(const float* __restrict__ in, const float* __restrict__ dinv,
                           const float* __restrict__ preb, const float* __restrict__ W,
                           float* __restrict__ hs, int N) {
    int t = blockIdx.x * blockDim.x + threadIdx.x;
    int i = t / FOUT, f = t % FOUT;
    if (i >= N) return;
    float di = dinv[i];
    float s = 0.f;
#pragma unroll 8
    for (int k = 0; k < FIN; ++k) {
        float v = in[(size_t)i * FIN + k];
        if (PRE) v = fmaxf(di * v + preb[k], 0.f);
        s += v * W[k * FOUT + f];
    }
    hs[(size_t)i * FOUT + f] = s * di;
}

// ---- gather aggregation: acc[i] = hs[i] + sum_{src in N(i)} hs[src] ------
// F lanes per node (f = feature); neighbor rows read contiguously, no atomics.
template <int F>
__global__ void gather_agg(const int* __restrict__ rowptr, const int* __restrict__ csr_src,
                           const float* __restrict__ hs, float* __restrict__ acc, int N) {
    const int NPB = 256 / F;  // nodes per block
    int tid = threadIdx.x;
    int i = blockIdx.x * NPB + tid / F;
    int f = tid % F;
    if (i >= N) return;
    float s = hs[(size_t)i * F + f];  // self-loop
    int start = rowptr[i], end = rowptr[i + 1];
    for (int j = start; j < end; ++j) {
        int srcn = csr_src[j];
        s += hs[(size_t)srcn * F + f];
    }
    acc[(size_t)i * F + f] = s;
}

// ---- layer-3 epilogue + segment-max pool ---------------------------------
// batch is SORTED: one wave handles 64 consecutive nodes, run-length max,
// one atomicMax per graph boundary. relu>=0 so float-as-uint max is valid.
__global__ void finish_pool(const float* __restrict__ acc, const float* __restrict__ dinv,
                            const float* __restrict__ b, const int* __restrict__ batch,
                            unsigned* __restrict__ pooled, int N) {
    int f = threadIdx.x;  // 64 threads
    int i0 = blockIdx.x * 64;
    float bf = b[f];
    int prevb = -1;
    float run = 0.f;
    for (int k = 0; k < 64; ++k) {
        int i = i0 + k;
        if (i >= N) break;
        int bg = batch[i];
        float v = fmaxf(dinv[i] * acc[(size_t)i * 64 + f] + bf, 0.f);
        if (bg != prevb) {
            if (prevb >= 0) atomicMax(&pooled[prevb * 64 + f], __float_as_uint(run));
            prevb = bg;
            run = v;
        } else {
            run = fmaxf(run, v);
        }
    }
    if (prevb >= 0) atomicMax(&pooled[prevb * 64 + f], __float_as_uint(run));
}

// ---- MLP head: one block (256 thr) per graph -----------------------------
__global__ void head(const float* __restrict__ pooled, const float* __restrict__ w1,
                     const float* __restrict__ bb1, const float* __restrict__ w2,
                     const float* __restrict__ bb2, float* __restrict__ out) {
    __shared__ float p[64];
    __shared__ float z[256];
    int g = blockIdx.x, t = threadIdx.x;
    if (t < 64) p[t] = pooled[g * 64 + t];
    __syncthreads();
    float s = bb1[t];
#pragma unroll
    for (int k = 0; k < 64; ++k) s += p[k] * w1[k * 256 + t];
    z[t] = fmaxf(s, 0.f);
    __syncthreads();
    float s2 = bb2[t];
#pragma unroll 8
    for (int k = 0; k < 256; ++k) s2 += z[k] * w2[k * 256 + t];
    out[g * 256 + t] = 1.f / (1.f + expf(-s2));
}

extern "C" void kernel_launch(void* const* d_in, const int* in_sizes, int n_in,
                              void* d_out, int out_size, void* d_ws, size_t ws_size,
                              hipStream_t stream) {
    const float* x   = (const float*)d_in[0];
    const int* ei    = (const int*)d_in[1];
    const int* batch = (const int*)d_in[2];
    const float* W1  = (const float*)d_in[3];
    const float* b1  = (const float*)d_in[4];
    const float* W2  = (const float*)d_in[5];
    const float* b2  = (const float*)d_in[6];
    const float* W3  = (const float*)d_in[7];
    const float* b3  = (const float*)d_in[8];
    const float* L1w = (const float*)d_in[9];
    const float* L1b = (const float*)d_in[10];
    const float* L2w = (const float*)d_in[11];
    const float* L2b = (const float*)d_in[12];

    const int N = in_sizes[0] / 128;
    const int E = in_sizes[1] / 2;
    const int* srcp = ei;
    const int* dstp = ei + E;

    // workspace layout (all 4B-typed)
    char* w = (char*)d_ws;
    int*   deg     = (int*)w;                 w += (size_t)N * 4;
    int*   rowptr  = (int*)w;                 w += (size_t)(N + 1) * 4;
    int*   cursor  = (int*)w;                 w += (size_t)N * 4;
    int*   csr_src = (int*)w;                 w += (size_t)E * 4;
    float* dinv    = (float*)w;               w += (size_t)N * 4;
    float* hs      = (float*)w;               w += (size_t)N * 64 * 4;
    float* acc     = (float*)w;               w += (size_t)N * 64 * 4;
    unsigned* pooled = (unsigned*)w;          w += (size_t)NG * 64 * 4;

    hipMemsetAsync(deg, 0, (size_t)N * sizeof(int), stream);
    hipMemsetAsync(cursor, 0, (size_t)N * sizeof(int), stream);
    hipMemsetAsync(pooled, 0, (size_t)NG * 64 * sizeof(unsigned), stream);

    deg_count<<<cdiv_i(E, 256), 256, 0, stream>>>(dstp, deg, E);
    scan_deg<<<1, 1024, 0, stream>>>(deg, rowptr, N);
    deg_to_dinv<<<cdiv_i(N, 256), 256, 0, stream>>>(deg, dinv, N);
    fill_csr<<<cdiv_i(E, 256), 256, 0, stream>>>(srcp, dstp, rowptr, cursor, csr_src, E);

    // Layer 1: x[128] -> 16
    gemm_scale<128, 16, false><<<cdiv_i((long long)N * 16, 256), 256, 0, stream>>>(
        x, dinv, nullptr, W1, hs, N);
    gather_agg<16><<<cdiv_i(N, 16), 256, 0, stream>>>(rowptr, csr_src, hs, acc, N);

    // Layer 2: 16 -> 32 (fused relu(dinv*acc+b1) on input)
    gemm_scale<16, 32, true><<<cdiv_i((long long)N * 32, 256), 256, 0, stream>>>(
        acc, dinv, b1, W2, hs, N);
    gather_agg<32><<<cdiv_i(N, 8), 256, 0, stream>>>(rowptr, csr_src, hs, acc, N);

    // Layer 3: 32 -> 64
    gemm_scale<32, 64, true><<<cdiv_i((long long)N * 64, 256), 256, 0, stream>>>(
        acc, dinv, b2, W3, hs, N);
    gather_agg<64><<<cdiv_i(N, 4), 256, 0, stream>>>(rowptr, csr_src, hs, acc, N);

    // pool + head
    finish_pool<<<cdiv_i(N, 64), 64, 0, stream>>>(acc, dinv, b3, batch, pooled, N);
    head<<<NG, 256, 0, stream>>>((const float*)pooled, L1w, L1b, L2w, L2b, (float*)d_out);
}

// Round 3
// 431.189 us; speedup vs baseline: 5.7491x; 1.7718x over previous
//
#include <hip/hip_runtime.h>
#include <math.h>

#define NG 1024  // NUM_GRAPHS

static inline int cdiv_i(long long a, int b) { return (int)((a + b - 1) / b); }

// ---- CSR build -----------------------------------------------------------
__global__ void deg_count(const int* __restrict__ dst, int* __restrict__ deg, int E) {
    int t = blockIdx.x * blockDim.x + threadIdx.x;
    if (t < E) atomicAdd(&deg[dst[t]], 1);
}

// 256-wide block sums
__global__ void bsum_reduce(const int* __restrict__ deg, int* __restrict__ bsums, int N) {
    __shared__ int s[256];
    int t = threadIdx.x, i = blockIdx.x * 256 + t;
    s[t] = (i < N) ? deg[i] : 0;
    __syncthreads();
    for (int off = 128; off > 0; off >>= 1) {
        if (t < off) s[t] += s[t + off];
        __syncthreads();
    }
    if (t == 0) bsums[blockIdx.x] = s[0];
}

// single block, 512 threads: exclusive scan of bsums[NB] in place (NB <= 512)
__global__ void bsum_scan(int* __restrict__ bsums, int NB) {
    __shared__ int s[512];
    int t = threadIdx.x;
    int v = (t < NB) ? bsums[t] : 0;
    s[t] = v;
    __syncthreads();
    for (int off = 1; off < 512; off <<= 1) {
        int u = (t >= off) ? s[t - off] : 0;
        __syncthreads();
        s[t] += u;
        __syncthreads();
    }
    if (t < NB) bsums[t] = s[t] - v;  // exclusive
}

// per-block rescan: rowptr + dinv fused
__global__ void csr_scan(const int* __restrict__ deg, const int* __restrict__ bsums,
                         int* __restrict__ rowptr, float* __restrict__ dinv, int N) {
    __shared__ int s[256];
    int t = threadIdx.x, i = blockIdx.x * 256 + t;
    int v = (i < N) ? deg[i] : 0;
    s[t] = v;
    __syncthreads();
    for (int off = 1; off < 256; off <<= 1) {
        int u = (t >= off) ? s[t - off] : 0;
        __syncthreads();
        s[t] += u;
        __syncthreads();
    }
    int base = bsums[blockIdx.x];
    if (i < N) {
        rowptr[i] = base + s[t] - v;
        dinv[i] = rsqrtf((float)(v + 1));  // +1 self-loop
        if (i == N - 1) rowptr[N] = base + s[t];
    }
}

__global__ void fill_csr(const int* __restrict__ src, const int* __restrict__ dst,
                         const int* __restrict__ rowptr, int* __restrict__ cursor,
                         int* __restrict__ csr_src, int E) {
    int e = blockIdx.x * blockDim.x + threadIdx.x;
    if (e >= E) return;
    int d = dst[e];
    int pos = atomicAdd(&cursor[d], 1);
    csr_src[rowptr[d] + pos] = src[e];
}

// ---- layer-1 GEMM: t[i][f] = dinv[i] * (x[i] @ W)[f] ---------------------
template <int FIN, int FOUT>
__global__ void gemm_in(const float* __restrict__ x, const float* __restrict__ dinv,
                        const float* __restrict__ W, float* __restrict__ out, int N) {
    int t = blockIdx.x * blockDim.x + threadIdx.x;
    int i = t / FOUT, f = t % FOUT;
    if (i >= N) return;
    const float4* x4 = (const float4*)(x + (size_t)i * FIN);
    float s = 0.f;
#pragma unroll
    for (int k4 = 0; k4 < FIN / 4; ++k4) {
        float4 v = x4[k4];
        int k = k4 * 4;
        s += v.x * W[k * FOUT + f] + v.y * W[(k + 1) * FOUT + f] +
             v.z * W[(k + 2) * FOUT + f] + v.w * W[(k + 3) * FOUT + f];
    }
    out[(size_t)i * FOUT + f] = dinv[i] * s;
}

// ---- post-aggregation GEMM: h = relu(di*(g@W)+b); out = SCALE_OUT? di*h : h
template <int FIN, int FOUT, bool SCALE_OUT>
__global__ void gemm_post(const float* __restrict__ g, const float* __restrict__ dinv,
                          const float* __restrict__ W, const float* __restrict__ b,
                          float* __restrict__ out, int N) {
    int t = blockIdx.x * blockDim.x + threadIdx.x;
    int i = t / FOUT, f = t % FOUT;
    if (i >= N) return;
    float di = dinv[i];
    const float4* g4 = (const float4*)(g + (size_t)i * FIN);
    float s = 0.f;
#pragma unroll
    for (int k4 = 0; k4 < FIN / 4; ++k4) {
        float4 v = g4[k4];
        int k = k4 * 4;
        s += v.x * W[k * FOUT + f] + v.y * W[(k + 1) * FOUT + f] +
             v.z * W[(k + 2) * FOUT + f] + v.w * W[(k + 3) * FOUT + f];
    }
    float h = fmaxf(di * s + b[f], 0.f);
    out[(size_t)i * FOUT + f] = SCALE_OUT ? di * h : h;
}

// ---- gather: g[i] = hs[i] + sum_{src in N(i)} hs[src], float4 lanes ------
// EPI: out = di*relu(di*g + b)   (layer-1 epilogue, produces p1)
template <int F, bool EPI>
__global__ void gather4(const int* __restrict__ rowptr, const int* __restrict__ csr_src,
                        const float* __restrict__ hs, const float* __restrict__ dinv,
                        const float* __restrict__ b, float* __restrict__ out, int N) {
    const int L = F / 4;
    int tid = blockIdx.x * 256 + threadIdx.x;
    int i = tid / L, c = tid % L;
    if (i >= N) return;
    const float4* hs4 = (const float4*)hs;
    float4 s = hs4[(size_t)i * L + c];  // self loop
    int j = rowptr[i], end = rowptr[i + 1];
#pragma unroll 2
    for (; j < end; ++j) {
        int srcn = csr_src[j];
        float4 v = hs4[(size_t)srcn * L + c];
        s.x += v.x; s.y += v.y; s.z += v.z; s.w += v.w;
    }
    if (EPI) {
        float di = dinv[i];
        float4 bb = ((const float4*)b)[c];
        s.x = di * fmaxf(di * s.x + bb.x, 0.f);
        s.y = di * fmaxf(di * s.y + bb.y, 0.f);
        s.z = di * fmaxf(di * s.z + bb.z, 0.f);
        s.w = di * fmaxf(di * s.w + bb.w, 0.f);
    }
    ((float4*)out)[(size_t)i * L + c] = s;
}

// ---- pool: batch sorted -> run-length max, one atomicMax per boundary ----
// h3 >= 0 (post-relu) so float-as-uint max with 0-init is exact.
__global__ void finish_pool(const float* __restrict__ h3, const int* __restrict__ batch,
                            unsigned* __restrict__ pooled, int N) {
    int f = threadIdx.x;  // 64
    int i0 = blockIdx.x * 64;
    int prevb = -1;
    float run = 0.f;
    for (int k = 0; k < 64; ++k) {
        int i = i0 + k;
        if (i >= N) break;
        int bg = batch[i];
        float v = h3[(size_t)i * 64 + f];
        if (bg != prevb) {
            if (prevb >= 0) atomicMax(&pooled[prevb * 64 + f], __float_as_uint(run));
            prevb = bg;
            run = v;
        } else {
            run = fmaxf(run, v);
        }
    }
    if (prevb >= 0) atomicMax(&pooled[prevb * 64 + f], __float_as_uint(run));
}

// ---- MLP head: one block (256 thr) per graph -----------------------------
__global__ void head(const float* __restrict__ pooled, const float* __restrict__ w1,
                     const float* __restrict__ bb1, const float* __restrict__ w2,
                     const float* __restrict__ bb2, float* __restrict__ out) {
    __shared__ float p[64];
    __shared__ float z[256];
    int g = blockIdx.x, t = threadIdx.x;
    if (t < 64) p[t] = pooled[g * 64 + t];
    __syncthreads();
    float s = bb1[t];
#pragma unroll
    for (int k = 0; k < 64; ++k) s += p[k] * w1[k * 256 + t];
    z[t] = fmaxf(s, 0.f);
    __syncthreads();
    float s2 = bb2[t];
#pragma unroll 8
    for (int k = 0; k < 256; ++k) s2 += z[k] * w2[k * 256 + t];
    out[g * 256 + t] = 1.f / (1.f + expf(-s2));
}

extern "C" void kernel_launch(void* const* d_in, const int* in_sizes, int n_in,
                              void* d_out, int out_size, void* d_ws, size_t ws_size,
                              hipStream_t stream) {
    const float* x   = (const float*)d_in[0];
    const int* ei    = (const int*)d_in[1];
    const int* batch = (const int*)d_in[2];
    const float* W1  = (const float*)d_in[3];
    const float* b1  = (const float*)d_in[4];
    const float* W2  = (const float*)d_in[5];
    const float* b2  = (const float*)d_in[6];
    const float* W3  = (const float*)d_in[7];
    const float* b3  = (const float*)d_in[8];
    const float* L1w = (const float*)d_in[9];
    const float* L1b = (const float*)d_in[10];
    const float* L2w = (const float*)d_in[11];
    const float* L2b = (const float*)d_in[12];

    const int N = in_sizes[0] / 128;
    const int E = in_sizes[1] / 2;
    const int* srcp = ei;
    const int* dstp = ei + E;
    const int NB = cdiv_i(N, 256);

    // workspace layout
    char* w = (char*)d_ws;
    int*   deg     = (int*)w;        w += (size_t)N * 4;
    int*   rowptr  = (int*)w;        w += (size_t)(N + 1) * 4;
    int*   cursor  = (int*)w;        w += (size_t)N * 4;
    int*   bsums   = (int*)w;        w += (size_t)512 * 4;
    int*   csr_src = (int*)w;        w += (size_t)E * 4;
    float* dinv    = (float*)w;      w += (size_t)N * 4;
    float* bufAB   = (float*)w;      w += (size_t)N * 32 * 4;  // two N*16 halves
    float* bufC    = (float*)w;      w += (size_t)N * 32 * 4;
    float* bufD    = (float*)w;      w += (size_t)N * 64 * 4;
    unsigned* pooled = (unsigned*)w; w += (size_t)NG * 64 * 4;
    float* bufA = bufAB;                   // N*16
    float* bufB = bufAB + (size_t)N * 16;  // N*16

    hipMemsetAsync(deg, 0, (size_t)N * sizeof(int), stream);
    hipMemsetAsync(cursor, 0, (size_t)N * sizeof(int), stream);
    hipMemsetAsync(pooled, 0, (size_t)NG * 64 * sizeof(unsigned), stream);

    deg_count<<<cdiv_i(E, 256), 256, 0, stream>>>(dstp, deg, E);
    bsum_reduce<<<NB, 256, 0, stream>>>(deg, bsums, N);
    bsum_scan<<<1, 512, 0, stream>>>(bsums, NB);
    csr_scan<<<NB, 256, 0, stream>>>(deg, bsums, rowptr, dinv, N);
    fill_csr<<<cdiv_i(E, 256), 256, 0, stream>>>(srcp, dstp, rowptr, cursor, csr_src, E);

    // Layer 1 (transform-first): t = dinv*(x@W1)  [N,16]
    gemm_in<128, 16><<<cdiv_i((long long)N * 16, 256), 256, 0, stream>>>(x, dinv, W1, bufA, N);
    // gather + epilogue -> p1 = dinv*relu(dinv*g + b1)  [N,16]
    gather4<16, true><<<cdiv_i((long long)N * 4, 256), 256, 0, stream>>>(
        rowptr, csr_src, bufA, dinv, b1, bufB, N);

    // Layer 2 (aggregate-first): g2 = p1 + sum p1[src]  [N,16]
    gather4<16, false><<<cdiv_i((long long)N * 4, 256), 256, 0, stream>>>(
        rowptr, csr_src, bufB, nullptr, nullptr, bufA, N);
    // p2 = dinv*relu(dinv*(g2@W2)+b2)  [N,32]
    gemm_post<16, 32, true><<<cdiv_i((long long)N * 32, 256), 256, 0, stream>>>(
        bufA, dinv, W2, b2, bufC, N);

    // Layer 3 (aggregate-first): g3 = p2 + sum p2[src]  [N,32]
    gather4<32, false><<<cdiv_i((long long)N * 8, 256), 256, 0, stream>>>(
        rowptr, csr_src, bufC, nullptr, nullptr, bufAB, N);
    // h3 = relu(dinv*(g3@W3)+b3)  [N,64]
    gemm_post<32, 64, false><<<cdiv_i((long long)N * 64, 256), 256, 0, stream>>>(
        bufAB, dinv, W3, b3, bufD, N);

    // pool + head
    finish_pool<<<cdiv_i(N, 64), 64, 0, stream>>>(bufD, batch, pooled, N);
    head<<<NG, 256, 0, stream>>>((const float*)pooled, L1w, L1b, L2w, L2b, (float*)d_out);
}

// Round 4
// 337.693 us; speedup vs baseline: 7.3408x; 1.2769x over previous
//
#include <hip/hip_runtime.h>
#include <math.h>

#define NG 1024  // NUM_GRAPHS

static inline int cdiv_i(long long a, int b) { return (int)((a + b - 1) / b); }

// ---- CSR build -----------------------------------------------------------
__global__ void deg_count(const int* __restrict__ dst, int* __restrict__ deg, int E) {
    int t = blockIdx.x * blockDim.x + threadIdx.x;
    if (t < E) atomicAdd(&deg[dst[t]], 1);
}

// 256-wide block sums
__global__ void bsum_reduce(const int* __restrict__ deg, int* __restrict__ bsums, int N) {
    __shared__ int s[256];
    int t = threadIdx.x, i = blockIdx.x * 256 + t;
    s[t] = (i < N) ? deg[i] : 0;
    __syncthreads();
    for (int off = 128; off > 0; off >>= 1) {
        if (t < off) s[t] += s[t + off];
        __syncthreads();
    }
    if (t == 0) bsums[blockIdx.x] = s[0];
}

// single block, 512 threads: exclusive scan of bsums[NB] in place (NB <= 512)
__global__ void bsum_scan(int* __restrict__ bsums, int NB) {
    __shared__ int s[512];
    int t = threadIdx.x;
    int v = (t < NB) ? bsums[t] : 0;
    s[t] = v;
    __syncthreads();
    for (int off = 1; off < 512; off <<= 1) {
        int u = (t >= off) ? s[t - off] : 0;
        __syncthreads();
        s[t] += u;
        __syncthreads();
    }
    if (t < NB) bsums[t] = s[t] - v;  // exclusive
}

// per-block rescan: rowptr + dinv fused
__global__ void csr_scan(const int* __restrict__ deg, const int* __restrict__ bsums,
                         int* __restrict__ rowptr, float* __restrict__ dinv, int N) {
    __shared__ int s[256];
    int t = threadIdx.x, i = blockIdx.x * 256 + t;
    int v = (i < N) ? deg[i] : 0;
    s[t] = v;
    __syncthreads();
    for (int off = 1; off < 256; off <<= 1) {
        int u = (t >= off) ? s[t - off] : 0;
        __syncthreads();
        s[t] += u;
        __syncthreads();
    }
    int base = bsums[blockIdx.x];
    if (i < N) {
        rowptr[i] = base + s[t] - v;
        dinv[i] = rsqrtf((float)(v + 1));  // +1 self-loop
        if (i == N - 1) rowptr[N] = base + s[t];
    }
}

// bucket b covers nodes [b*512, (b+1)*512); bktcur[b] = rowptr[b*512]
__global__ void init_bktcur(const int* __restrict__ rowptr, int* __restrict__ bktcur, int N) {
    int t = threadIdx.x;  // 256
    bktcur[t] = rowptr[min(N, t << 9)];
}

// Phase 1: block-local counting sort of 8192-edge chunks into 256 buckets.
#define EPB 8192
__global__ void bin_edges(const int* __restrict__ src, const int* __restrict__ dst,
                          int* __restrict__ bktcur, int2* __restrict__ binned, int E) {
    __shared__ int hist[256];
    __shared__ int gbase[256];
    __shared__ int lcur[256];
    int t = threadIdx.x;
    hist[t] = 0;
    lcur[t] = 0;
    __syncthreads();
    int e0 = blockIdx.x * EPB;
#pragma unroll 4
    for (int k = 0; k < EPB / 256; ++k) {
        int e = e0 + k * 256 + t;
        if (e < E) atomicAdd(&hist[dst[e] >> 9], 1);
    }
    __syncthreads();
    if (hist[t] > 0) gbase[t] = atomicAdd(&bktcur[t], hist[t]);
    __syncthreads();
#pragma unroll 4
    for (int k = 0; k < EPB / 256; ++k) {
        int e = e0 + k * 256 + t;
        if (e < E) {
            int d = dst[e];
            int b = d >> 9;
            int r = atomicAdd(&lcur[b], 1);
            binned[gbase[b] + r] = make_int2(src[e], d);
        }
    }
}

// Phase 2: one block per bucket; scatter within private 32KB csr window.
__global__ void fill_csr_bucketed(const int* __restrict__ rowptr, const int2* __restrict__ binned,
                                  int* __restrict__ csr_src, int N) {
    __shared__ int cur[512];
    __shared__ int rp[513];
    int t = threadIdx.x;  // 256
    int n0 = blockIdx.x << 9;
    cur[t] = 0;
    cur[t + 256] = 0;
    rp[t] = rowptr[min(N, n0 + t)];
    rp[t + 256] = rowptr[min(N, n0 + t + 256)];
    if (t == 0) rp[512] = rowptr[min(N, n0 + 512)];
    __syncthreads();
    int n1 = min(N, n0 + 512);
    int base = rp[0], end = rp[n1 - n0];
    for (int j = base + t; j < end; j += 256) {
        int2 e = binned[j];
        int li = e.y - n0;
        int slot = rp[li] + atomicAdd(&cur[li], 1);
        csr_src[slot] = e.x;
    }
}

// ---- layer-1 GEMM (thread-per-node, W in LDS): out = dinv[i]*(x[i]@W) ----
template <int FIN, int FOUT>
__global__ void gemm_in_tpn(const float* __restrict__ x, const float* __restrict__ dinv,
                            const float* __restrict__ W, float* __restrict__ out, int N) {
    __shared__ float Wl[FIN * FOUT];
    int t = threadIdx.x;
    for (int k = t; k < FIN * FOUT; k += 256) Wl[k] = W[k];
    __syncthreads();
    int i = blockIdx.x * 256 + t;
    if (i >= N) return;
    const float4* x4 = (const float4*)(x + (size_t)i * FIN);
    const float4* W4 = (const float4*)Wl;
    float4 a[FOUT / 4];
#pragma unroll
    for (int c = 0; c < FOUT / 4; ++c) a[c] = make_float4(0.f, 0.f, 0.f, 0.f);
#pragma unroll 4
    for (int k4 = 0; k4 < FIN / 4; ++k4) {
        float4 v = x4[k4];
#pragma unroll
        for (int kk = 0; kk < 4; ++kk) {
            float xk = (kk == 0) ? v.x : (kk == 1) ? v.y : (kk == 2) ? v.z : v.w;
            const float4* Wr = W4 + (k4 * 4 + kk) * (FOUT / 4);
#pragma unroll
            for (int c = 0; c < FOUT / 4; ++c) {
                float4 w = Wr[c];
                a[c].x += xk * w.x; a[c].y += xk * w.y;
                a[c].z += xk * w.z; a[c].w += xk * w.w;
            }
        }
    }
    float di = dinv[i];
    float4* o4 = (float4*)(out + (size_t)i * FOUT);
#pragma unroll
    for (int c = 0; c < FOUT / 4; ++c) {
        float4 r;
        r.x = di * a[c].x; r.y = di * a[c].y; r.z = di * a[c].z; r.w = di * a[c].w;
        o4[c] = r;
    }
}

// ---- post-agg GEMM (thread-per-node): h=relu(di*(g@W)+b); out = SCALE?di*h:h
template <int FIN, int FOUT, bool SCALE_OUT>
__global__ void gemm_post_tpn(const float* __restrict__ g, const float* __restrict__ dinv,
                              const float* __restrict__ W, const float* __restrict__ b,
                              float* __restrict__ out, int N) {
    __shared__ float Wl[FIN * FOUT];
    __shared__ float bl[FOUT];
    int t = threadIdx.x;
    for (int k = t; k < FIN * FOUT; k += 256) Wl[k] = W[k];
    if (t < FOUT) bl[t] = b[t];
    __syncthreads();
    int i = blockIdx.x * 256 + t;
    if (i >= N) return;
    const float4* g4 = (const float4*)(g + (size_t)i * FIN);
    const float4* W4 = (const float4*)Wl;
    float4 a[FOUT / 4];
#pragma unroll
    for (int c = 0; c < FOUT / 4; ++c) a[c] = make_float4(0.f, 0.f, 0.f, 0.f);
#pragma unroll 4
    for (int k4 = 0; k4 < FIN / 4; ++k4) {
        float4 v = g4[k4];
#pragma unroll
        for (int kk = 0; kk < 4; ++kk) {
            float xk = (kk == 0) ? v.x : (kk == 1) ? v.y : (kk == 2) ? v.z : v.w;
            const float4* Wr = W4 + (k4 * 4 + kk) * (FOUT / 4);
#pragma unroll
            for (int c = 0; c < FOUT / 4; ++c) {
                float4 w = Wr[c];
                a[c].x += xk * w.x; a[c].y += xk * w.y;
                a[c].z += xk * w.z; a[c].w += xk * w.w;
            }
        }
    }
    float di = dinv[i];
    const float4* b4 = (const float4*)bl;
    float4* o4 = (float4*)(out + (size_t)i * FOUT);
#pragma unroll
    for (int c = 0; c < FOUT / 4; ++c) {
        float4 bb = b4[c];
        float4 r;
        r.x = fmaxf(di * a[c].x + bb.x, 0.f);
        r.y = fmaxf(di * a[c].y + bb.y, 0.f);
        r.z = fmaxf(di * a[c].z + bb.z, 0.f);
        r.w = fmaxf(di * a[c].w + bb.w, 0.f);
        if (SCALE_OUT) { r.x *= di; r.y *= di; r.z *= di; r.w *= di; }
        o4[c] = r;
    }
}

// ---- gather: g[i] = hs[i] + sum_{src in N(i)} hs[src], float4 lanes ------
// EPI: out = di*relu(di*g + b)   (layer-1 epilogue, produces p1)
template <int F, bool EPI>
__global__ void gather4(const int* __restrict__ rowptr, const int* __restrict__ csr_src,
                        const float* __restrict__ hs, const float* __restrict__ dinv,
                        const float* __restrict__ b, float* __restrict__ out, int N) {
    const int L = F / 4;
    int tid = blockIdx.x * 256 + threadIdx.x;
    int i = tid / L, c = tid % L;
    if (i >= N) return;
    const float4* hs4 = (const float4*)hs;
    float4 s = hs4[(size_t)i * L + c];  // self loop
    int j = rowptr[i], end = rowptr[i + 1];
#pragma unroll 2
    for (; j < end; ++j) {
        int srcn = csr_src[j];
        float4 v = hs4[(size_t)srcn * L + c];
        s.x += v.x; s.y += v.y; s.z += v.z; s.w += v.w;
    }
    if (EPI) {
        float di = dinv[i];
        float4 bb = ((const float4*)b)[c];
        s.x = di * fmaxf(di * s.x + bb.x, 0.f);
        s.y = di * fmaxf(di * s.y + bb.y, 0.f);
        s.z = di * fmaxf(di * s.z + bb.z, 0.f);
        s.w = di * fmaxf(di * s.w + bb.w, 0.f);
    }
    ((float4*)out)[(size_t)i * L + c] = s;
}

// ---- pool: batch sorted -> run-length max, one atomicMax per boundary ----
__global__ void finish_pool(const float* __restrict__ h3, const int* __restrict__ batch,
                            unsigned* __restrict__ pooled, int N) {
    int f = threadIdx.x;  // 64
    int i0 = blockIdx.x * 64;
    int prevb = -1;
    float run = 0.f;
    for (int k = 0; k < 64; ++k) {
        int i = i0 + k;
        if (i >= N) break;
        int bg = batch[i];
        float v = h3[(size_t)i * 64 + f];
        if (bg != prevb) {
            if (prevb >= 0) atomicMax(&pooled[prevb * 64 + f], __float_as_uint(run));
            prevb = bg;
            run = v;
        } else {
            run = fmaxf(run, v);
        }
    }
    if (prevb >= 0) atomicMax(&pooled[prevb * 64 + f], __float_as_uint(run));
}

// ---- MLP head: one block (256 thr) per graph -----------------------------
__global__ void head(const float* __restrict__ pooled, const float* __restrict__ w1,
                     const float* __restrict__ bb1, const float* __restrict__ w2,
                     const float* __restrict__ bb2, float* __restrict__ out) {
    __shared__ float p[64];
    __shared__ float z[256];
    int g = blockIdx.x, t = threadIdx.x;
    if (t < 64) p[t] = pooled[g * 64 + t];
    __syncthreads();
    float s = bb1[t];
#pragma unroll
    for (int k = 0; k < 64; ++k) s += p[k] * w1[k * 256 + t];
    z[t] = fmaxf(s, 0.f);
    __syncthreads();
    float s2 = bb2[t];
#pragma unroll 8
    for (int k = 0; k < 256; ++k) s2 += z[k] * w2[k * 256 + t];
    out[g * 256 + t] = 1.f / (1.f + expf(-s2));
}

extern "C" void kernel_launch(void* const* d_in, const int* in_sizes, int n_in,
                              void* d_out, int out_size, void* d_ws, size_t ws_size,
                              hipStream_t stream) {
    const float* x   = (const float*)d_in[0];
    const int* ei    = (const int*)d_in[1];
    const int* batch = (const int*)d_in[2];
    const float* W1  = (const float*)d_in[3];
    const float* b1  = (const float*)d_in[4];
    const float* W2  = (const float*)d_in[5];
    const float* b2  = (const float*)d_in[6];
    const float* W3  = (const float*)d_in[7];
    const float* b3  = (const float*)d_in[8];
    const float* L1w = (const float*)d_in[9];
    const float* L1b = (const float*)d_in[10];
    const float* L2w = (const float*)d_in[11];
    const float* L2b = (const float*)d_in[12];

    const int N = in_sizes[0] / 128;
    const int E = in_sizes[1] / 2;
    const int* srcp = ei;
    const int* dstp = ei + E;
    const int NB = cdiv_i(N, 256);
    const int NBKT = cdiv_i(N, 512);

    // workspace layout
    char* w = (char*)d_ws;
    int*   deg     = (int*)w;        w += (size_t)N * 4;
    int*   rowptr  = (int*)w;        w += (size_t)(N + 1) * 4;
    int*   bsums   = (int*)w;        w += (size_t)512 * 4;
    int*   bktcur  = (int*)w;        w += (size_t)256 * 4;
    int*   csr_src = (int*)w;        w += (size_t)E * 4;
    float* dinv    = (float*)w;      w += (size_t)N * 4;
    float* bufAB   = (float*)w;      w += (size_t)N * 32 * 4;  // two N*16 halves
    float* bufC    = (float*)w;      w += (size_t)N * 32 * 4;
    float* bufD    = (float*)w;      w += (size_t)N * 64 * 4;  // aliased: binned int2[E]
    unsigned* pooled = (unsigned*)w; w += (size_t)NG * 64 * 4;
    float* bufA = bufAB;                   // N*16
    float* bufB = bufAB + (size_t)N * 16;  // N*16
    int2* binned = (int2*)bufD;            // E int2 = 12.8MB <= 25.6MB

    hipMemsetAsync(deg, 0, (size_t)N * sizeof(int), stream);
    hipMemsetAsync(pooled, 0, (size_t)NG * 64 * sizeof(unsigned), stream);

    deg_count<<<cdiv_i(E, 256), 256, 0, stream>>>(dstp, deg, E);
    bsum_reduce<<<NB, 256, 0, stream>>>(deg, bsums, N);
    bsum_scan<<<1, 512, 0, stream>>>(bsums, NB);
    csr_scan<<<NB, 256, 0, stream>>>(deg, bsums, rowptr, dinv, N);
    init_bktcur<<<1, 256, 0, stream>>>(rowptr, bktcur, N);
    bin_edges<<<cdiv_i(E, EPB), 256, 0, stream>>>(srcp, dstp, bktcur, binned, E);
    fill_csr_bucketed<<<NBKT, 256, 0, stream>>>(rowptr, binned, csr_src, N);

    // Layer 1 (transform-first): t = dinv*(x@W1)  [N,16]
    gemm_in_tpn<128, 16><<<NB, 256, 0, stream>>>(x, dinv, W1, bufA, N);
    // gather + epilogue -> p1 = dinv*relu(dinv*g + b1)  [N,16]
    gather4<16, true><<<cdiv_i((long long)N * 4, 256), 256, 0, stream>>>(
        rowptr, csr_src, bufA, dinv, b1, bufB, N);

    // Layer 2 (aggregate-first): g2 = p1 + sum p1[src]  [N,16]
    gather4<16, false><<<cdiv_i((long long)N * 4, 256), 256, 0, stream>>>(
        rowptr, csr_src, bufB, nullptr, nullptr, bufA, N);
    // p2 = dinv*relu(dinv*(g2@W2)+b2)  [N,32]
    gemm_post_tpn<16, 32, true><<<NB, 256, 0, stream>>>(bufA, dinv, W2, b2, bufC, N);

    // Layer 3 (aggregate-first): g3 = p2 + sum p2[src]  [N,32]
    gather4<32, false><<<cdiv_i((long long)N * 8, 256), 256, 0, stream>>>(
        rowptr, csr_src, bufC, nullptr, nullptr, bufAB, N);
    // h3 = relu(dinv*(g3@W3)+b3)  [N,64]  (note: bufD free again after fill)
    gemm_post_tpn<32, 64, false><<<NB, 256, 0, stream>>>(bufAB, dinv, W3, b3, bufD, N);

    // pool + head
    finish_pool<<<cdiv_i(N, 64), 64, 0, stream>>>(bufD, batch, pooled, N);
    head<<<NG, 256, 0, stream>>>((const float*)pooled, L1w, L1b, L2w, L2b, (float*)d_out);
}

// Round 5
// 273.546 us; speedup vs baseline: 9.0623x; 1.2345x over previous
//
#include <hip/hip_runtime.h>
#include <math.h>

#define NG 1024   // NUM_GRAPHS
#define EPB 8192  // edges per binning block

static inline int cdiv_i(long long a, int b) { return (int)((a + b - 1) / b); }

// ---- CSR build (bucketed, no per-node global atomics) --------------------
// bucket b = nodes [b*512, (b+1)*512)

__global__ void bucket_count(const int* __restrict__ dst, int* __restrict__ bcnt, int E) {
    __shared__ int h[256];
    int t = threadIdx.x;
    h[t] = 0;
    __syncthreads();
    int e0 = blockIdx.x * EPB;
#pragma unroll 4
    for (int k = 0; k < EPB / 256; ++k) {
        int e = e0 + k * 256 + t;
        if (e < E) atomicAdd(&h[dst[e] >> 9], 1);
    }
    __syncthreads();
    if (h[t] > 0) atomicAdd(&bcnt[t], h[t]);
}

// single block, 256 threads: exclusive scan of bcnt[NBKT] -> bktbase/bktcur
__global__ void bucket_scan(const int* __restrict__ bcnt, int* __restrict__ bktbase,
                            int* __restrict__ bktcur, int* __restrict__ rowptr,
                            int NBKT, int N) {
    __shared__ int s[256];
    int t = threadIdx.x;
    int v = (t < NBKT) ? bcnt[t] : 0;
    s[t] = v;
    __syncthreads();
    for (int off = 1; off < 256; off <<= 1) {
        int u = (t >= off) ? s[t - off] : 0;
        __syncthreads();
        s[t] += u;
        __syncthreads();
    }
    int excl = s[t] - v;
    if (t < NBKT) { bktbase[t] = excl; bktcur[t] = excl; }
    if (t == 255) { bktbase[NBKT] = s[255]; rowptr[N] = s[255]; }
}

// bin edges into bucket-major order; entry packed = (dst&511)<<23 | src
__global__ void bin_edges(const int* __restrict__ src, const int* __restrict__ dst,
                          int* __restrict__ bktcur, unsigned* __restrict__ binned, int E) {
    __shared__ int hist[256];
    __shared__ int gbase[256];
    __shared__ int lcur[256];
    int t = threadIdx.x;
    hist[t] = 0;
    lcur[t] = 0;
    __syncthreads();
    int e0 = blockIdx.x * EPB;
#pragma unroll 4
    for (int k = 0; k < EPB / 256; ++k) {
        int e = e0 + k * 256 + t;
        if (e < E) atomicAdd(&hist[dst[e] >> 9], 1);
    }
    __syncthreads();
    if (hist[t] > 0) gbase[t] = atomicAdd(&bktcur[t], hist[t]);
    __syncthreads();
#pragma unroll 4
    for (int k = 0; k < EPB / 256; ++k) {
        int e = e0 + k * 256 + t;
        if (e < E) {
            int d = dst[e];
            int b = d >> 9;
            int r = atomicAdd(&lcur[b], 1);
            binned[gbase[b] + r] = ((unsigned)(d & 511) << 23) | (unsigned)src[e];
        }
    }
}

// one 512-thread block per bucket: count LDS degrees, scan, write rowptr+dinv,
// scatter csr_src within private window.
__global__ void bucket_build(const int* __restrict__ bktbase, const unsigned* __restrict__ binned,
                             int* __restrict__ rowptr, float* __restrict__ dinv,
                             int* __restrict__ csr_src, int N) {
    __shared__ int degl[512];
    __shared__ int s[512];
    __shared__ int rp[512];
    __shared__ int cur[512];
    int t = threadIdx.x;  // 512
    int n0 = blockIdx.x << 9;
    degl[t] = 0;
    cur[t] = 0;
    __syncthreads();
    int base = bktbase[blockIdx.x], end = bktbase[blockIdx.x + 1];
    for (int j = base + t; j < end; j += 512) {
        unsigned v = binned[j];
        atomicAdd(&degl[v >> 23], 1);
    }
    __syncthreads();
    int d = degl[t];
    s[t] = d;
    __syncthreads();
    for (int off = 1; off < 512; off <<= 1) {
        int u = (t >= off) ? s[t - off] : 0;
        __syncthreads();
        s[t] += u;
        __syncthreads();
    }
    rp[t] = base + s[t] - d;  // exclusive
    int i = n0 + t;
    if (i < N) {
        rowptr[i] = rp[t];
        dinv[i] = rsqrtf((float)(d + 1));  // +1 self-loop
    }
    __syncthreads();
    for (int j = base + t; j < end; j += 512) {
        unsigned v = binned[j];
        int li = v >> 23;
        int slot = rp[li] + atomicAdd(&cur[li], 1);
        csr_src[slot] = (int)(v & 0x7FFFFFu);
    }
}

// ---- layer-1 GEMM (thread-per-node, W in LDS): out = dinv[i]*(x[i]@W) ----
template <int FIN, int FOUT>
__global__ void gemm_in_tpn(const float* __restrict__ x, const float* __restrict__ dinv,
                            const float* __restrict__ W, float* __restrict__ out, int N) {
    __shared__ float Wl[FIN * FOUT];
    int t = threadIdx.x;
    for (int k = t; k < FIN * FOUT; k += 256) Wl[k] = W[k];
    __syncthreads();
    int i = blockIdx.x * 256 + t;
    if (i >= N) return;
    const float4* x4 = (const float4*)(x + (size_t)i * FIN);
    const float4* W4 = (const float4*)Wl;
    float4 a[FOUT / 4];
#pragma unroll
    for (int c = 0; c < FOUT / 4; ++c) a[c] = make_float4(0.f, 0.f, 0.f, 0.f);
#pragma unroll 4
    for (int k4 = 0; k4 < FIN / 4; ++k4) {
        float4 v = x4[k4];
#pragma unroll
        for (int kk = 0; kk < 4; ++kk) {
            float xk = (kk == 0) ? v.x : (kk == 1) ? v.y : (kk == 2) ? v.z : v.w;
            const float4* Wr = W4 + (k4 * 4 + kk) * (FOUT / 4);
#pragma unroll
            for (int c = 0; c < FOUT / 4; ++c) {
                float4 w = Wr[c];
                a[c].x += xk * w.x; a[c].y += xk * w.y;
                a[c].z += xk * w.z; a[c].w += xk * w.w;
            }
        }
    }
    float di = dinv[i];
    float4* o4 = (float4*)(out + (size_t)i * FOUT);
#pragma unroll
    for (int c = 0; c < FOUT / 4; ++c) {
        float4 r;
        r.x = di * a[c].x; r.y = di * a[c].y; r.z = di * a[c].z; r.w = di * a[c].w;
        o4[c] = r;
    }
}

// ---- post-agg GEMM (thread-per-node): h=relu(di*(g@W)+b); out = SCALE?di*h:h
template <int FIN, int FOUT, bool SCALE_OUT>
__global__ void gemm_post_tpn(const float* __restrict__ g, const float* __restrict__ dinv,
                              const float* __restrict__ W, const float* __restrict__ b,
                              float* __restrict__ out, int N) {
    __shared__ float Wl[FIN * FOUT];
    __shared__ float bl[FOUT];
    int t = threadIdx.x;
    for (int k = t; k < FIN * FOUT; k += 256) Wl[k] = W[k];
    if (t < FOUT) bl[t] = b[t];
    __syncthreads();
    int i = blockIdx.x * 256 + t;
    if (i >= N) return;
    const float4* g4 = (const float4*)(g + (size_t)i * FIN);
    const float4* W4 = (const float4*)Wl;
    float4 a[FOUT / 4];
#pragma unroll
    for (int c = 0; c < FOUT / 4; ++c) a[c] = make_float4(0.f, 0.f, 0.f, 0.f);
#pragma unroll 4
    for (int k4 = 0; k4 < FIN / 4; ++k4) {
        float4 v = g4[k4];
#pragma unroll
        for (int kk = 0; kk < 4; ++kk) {
            float xk = (kk == 0) ? v.x : (kk == 1) ? v.y : (kk == 2) ? v.z : v.w;
            const float4* Wr = W4 + (k4 * 4 + kk) * (FOUT / 4);
#pragma unroll
            for (int c = 0; c < FOUT / 4; ++c) {
                float4 w = Wr[c];
                a[c].x += xk * w.x; a[c].y += xk * w.y;
                a[c].z += xk * w.z; a[c].w += xk * w.w;
            }
        }
    }
    float di = dinv[i];
    const float4* b4 = (const float4*)bl;
    float4* o4 = (float4*)(out + (size_t)i * FOUT);
#pragma unroll
    for (int c = 0; c < FOUT / 4; ++c) {
        float4 bb = b4[c];
        float4 r;
        r.x = fmaxf(di * a[c].x + bb.x, 0.f);
        r.y = fmaxf(di * a[c].y + bb.y, 0.f);
        r.z = fmaxf(di * a[c].z + bb.z, 0.f);
        r.w = fmaxf(di * a[c].w + bb.w, 0.f);
        if (SCALE_OUT) { r.x *= di; r.y *= di; r.z *= di; r.w *= di; }
        o4[c] = r;
    }
}

// ---- gather: g[i] = hs[i] + sum_{src in N(i)} hs[src], float4 lanes ------
// EPI: out = di*relu(di*g + b)   (layer-1 epilogue, produces p1)
template <int F, bool EPI>
__global__ void gather4(const int* __restrict__ rowptr, const int* __restrict__ csr_src,
                        const float* __restrict__ hs, const float* __restrict__ dinv,
                        const float* __restrict__ b, float* __restrict__ out, int N) {
    const int L = F / 4;
    int tid = blockIdx.x * 256 + threadIdx.x;
    int i = tid / L, c = tid % L;
    if (i >= N) return;
    const float4* hs4 = (const float4*)hs;
    float4 s = hs4[(size_t)i * L + c];  // self loop
    int j = rowptr[i], end = rowptr[i + 1];
#pragma unroll 2
    for (; j < end; ++j) {
        int srcn = csr_src[j];
        float4 v = hs4[(size_t)srcn * L + c];
        s.x += v.x; s.y += v.y; s.z += v.z; s.w += v.w;
    }
    if (EPI) {
        float di = dinv[i];
        float4 bb = ((const float4*)b)[c];
        s.x = di * fmaxf(di * s.x + bb.x, 0.f);
        s.y = di * fmaxf(di * s.y + bb.y, 0.f);
        s.z = di * fmaxf(di * s.z + bb.z, 0.f);
        s.w = di * fmaxf(di * s.w + bb.w, 0.f);
    }
    ((float4*)out)[(size_t)i * L + c] = s;
}

// ---- pool: batch sorted -> run-length max, one atomicMax per boundary ----
__global__ void finish_pool(const float* __restrict__ h3, const int* __restrict__ batch,
                            unsigned* __restrict__ pooled, int N) {
    int f = threadIdx.x;  // 64
    int i0 = blockIdx.x * 64;
    int prevb = -1;
    float run = 0.f;
    for (int k = 0; k < 64; ++k) {
        int i = i0 + k;
        if (i >= N) break;
        int bg = batch[i];
        float v = h3[(size_t)i * 64 + f];
        if (bg != prevb) {
            if (prevb >= 0) atomicMax(&pooled[prevb * 64 + f], __float_as_uint(run));
            prevb = bg;
            run = v;
        } else {
            run = fmaxf(run, v);
        }
    }
    if (prevb >= 0) atomicMax(&pooled[prevb * 64 + f], __float_as_uint(run));
}

// ---- MLP head: one block (256 thr) per graph -----------------------------
__global__ void head(const float* __restrict__ pooled, const float* __restrict__ w1,
                     const float* __restrict__ bb1, const float* __restrict__ w2,
                     const float* __restrict__ bb2, float* __restrict__ out) {
    __shared__ float p[64];
    __shared__ float z[256];
    int g = blockIdx.x, t = threadIdx.x;
    if (t < 64) p[t] = pooled[g * 64 + t];
    __syncthreads();
    float s = bb1[t];
#pragma unroll
    for (int k = 0; k < 64; ++k) s += p[k] * w1[k * 256 + t];
    z[t] = fmaxf(s, 0.f);
    __syncthreads();
    float s2 = bb2[t];
#pragma unroll 8
    for (int k = 0; k < 256; ++k) s2 += z[k] * w2[k * 256 + t];
    out[g * 256 + t] = 1.f / (1.f + expf(-s2));
}

extern "C" void kernel_launch(void* const* d_in, const int* in_sizes, int n_in,
                              void* d_out, int out_size, void* d_ws, size_t ws_size,
                              hipStream_t stream) {
    const float* x   = (const float*)d_in[0];
    const int* ei    = (const int*)d_in[1];
    const int* batch = (const int*)d_in[2];
    const float* W1  = (const float*)d_in[3];
    const float* b1  = (const float*)d_in[4];
    const float* W2  = (const float*)d_in[5];
    const float* b2  = (const float*)d_in[6];
    const float* W3  = (const float*)d_in[7];
    const float* b3  = (const float*)d_in[8];
    const float* L1w = (const float*)d_in[9];
    const float* L1b = (const float*)d_in[10];
    const float* L2w = (const float*)d_in[11];
    const float* L2b = (const float*)d_in[12];

    const int N = in_sizes[0] / 128;
    const int E = in_sizes[1] / 2;
    const int* srcp = ei;
    const int* dstp = ei + E;
    const int NB = cdiv_i(N, 256);
    const int NBKT = cdiv_i(N, 512);  // <= 256

    // workspace layout
    char* w = (char*)d_ws;
    int*   bcnt    = (int*)w;        w += (size_t)256 * 4;
    int*   bktbase = (int*)w;        w += (size_t)257 * 4;
    int*   bktcur  = (int*)w;        w += (size_t)256 * 4;
    int*   rowptr  = (int*)w;        w += (size_t)(N + 1) * 4;
    int*   csr_src = (int*)w;        w += (size_t)E * 4;
    float* dinv    = (float*)w;      w += (size_t)N * 4;
    float* bufAB   = (float*)w;      w += (size_t)N * 32 * 4;  // two N*16 halves
    float* bufC    = (float*)w;      w += (size_t)N * 32 * 4;
    float* bufD    = (float*)w;      w += (size_t)N * 64 * 4;  // aliased: binned uint[E]
    unsigned* pooled = (unsigned*)w; w += (size_t)NG * 64 * 4;
    float* bufA = bufAB;                   // N*16
    float* bufB = bufAB + (size_t)N * 16;  // N*16
    unsigned* binned = (unsigned*)bufD;    // E uint = 6.4MB <= 25.6MB

    hipMemsetAsync(bcnt, 0, 256 * sizeof(int), stream);
    hipMemsetAsync(pooled, 0, (size_t)NG * 64 * sizeof(unsigned), stream);

    bucket_count<<<cdiv_i(E, EPB), 256, 0, stream>>>(dstp, bcnt, E);
    bucket_scan<<<1, 256, 0, stream>>>(bcnt, bktbase, bktcur, rowptr, NBKT, N);
    bin_edges<<<cdiv_i(E, EPB), 256, 0, stream>>>(srcp, dstp, bktcur, binned, E);
    bucket_build<<<NBKT, 512, 0, stream>>>(bktbase, binned, rowptr, dinv, csr_src, N);

    // Layer 1 (transform-first): t = dinv*(x@W1)  [N,16]
    gemm_in_tpn<128, 16><<<NB, 256, 0, stream>>>(x, dinv, W1, bufA, N);
    // gather + epilogue -> p1 = dinv*relu(dinv*g + b1)  [N,16]
    gather4<16, true><<<cdiv_i((long long)N * 4, 256), 256, 0, stream>>>(
        rowptr, csr_src, bufA, dinv, b1, bufB, N);

    // Layer 2 (aggregate-first): g2 = p1 + sum p1[src]  [N,16]
    gather4<16, false><<<cdiv_i((long long)N * 4, 256), 256, 0, stream>>>(
        rowptr, csr_src, bufB, nullptr, nullptr, bufA, N);
    // p2 = dinv*relu(dinv*(g2@W2)+b2)  [N,32]
    gemm_post_tpn<16, 32, true><<<NB, 256, 0, stream>>>(bufA, dinv, W2, b2, bufC, N);

    // Layer 3 (aggregate-first): g3 = p2 + sum p2[src]  [N,32]
    gather4<32, false><<<cdiv_i((long long)N * 8, 256), 256, 0, stream>>>(
        rowptr, csr_src, bufC, nullptr, nullptr, bufAB, N);
    // h3 = relu(dinv*(g3@W3)+b3)  [N,64]  (bufD free again after bucket_build)
    gemm_post_tpn<32, 64, false><<<NB, 256, 0, stream>>>(bufAB, dinv, W3, b3, bufD, N);

    // pool + head
    finish_pool<<<cdiv_i(N, 64), 64, 0, stream>>>(bufD, batch, pooled, N);
    head<<<NG, 256, 0, stream>>>((const float*)pooled, L1w, L1b, L2w, L2b, (float*)d_out);
}

// Round 6
// 260.585 us; speedup vs baseline: 9.5130x; 1.0497x over previous
//
#include <hip/hip_runtime.h>
#include <hip/hip_fp16.h>
#include <math.h>

#define NG 1024   // NUM_GRAPHS
#define EPB 8192  // edges per binning block

static inline int cdiv_i(long long a, int b) { return (int)((a + b - 1) / b); }

// ---- fp16 pack/unpack helpers (8 halves per uint4) -----------------------
union H8 { uint4 u; __half2 h[4]; };

__device__ inline void h8_to_f(uint4 uu, float* f) {
    H8 v; v.u = uu;
#pragma unroll
    for (int k = 0; k < 4; ++k) {
        float2 t = __half22float2(v.h[k]);
        f[2 * k] = t.x; f[2 * k + 1] = t.y;
    }
}
__device__ inline uint4 f_to_h8(const float* f) {
    H8 v;
#pragma unroll
    for (int k = 0; k < 4; ++k) v.h[k] = __floats2half2_rn(f[2 * k], f[2 * k + 1]);
    return v.u;
}

// ---- CSR build (bucketed, no per-node global atomics) --------------------
// bucket b = nodes [b*512, (b+1)*512)

__global__ void bucket_count(const int* __restrict__ dst, int* __restrict__ bcnt, int E) {
    __shared__ int h[256];
    int t = threadIdx.x;
    h[t] = 0;
    __syncthreads();
    int e0 = blockIdx.x * EPB;
#pragma unroll 4
    for (int k = 0; k < EPB / 256; ++k) {
        int e = e0 + k * 256 + t;
        if (e < E) atomicAdd(&h[dst[e] >> 9], 1);
    }
    __syncthreads();
    if (h[t] > 0) atomicAdd(&bcnt[t], h[t]);
}

__global__ void bucket_scan(const int* __restrict__ bcnt, int* __restrict__ bktbase,
                            int* __restrict__ bktcur, int* __restrict__ rowptr,
                            int NBKT, int N) {
    __shared__ int s[256];
    int t = threadIdx.x;
    int v = (t < NBKT) ? bcnt[t] : 0;
    s[t] = v;
    __syncthreads();
    for (int off = 1; off < 256; off <<= 1) {
        int u = (t >= off) ? s[t - off] : 0;
        __syncthreads();
        s[t] += u;
        __syncthreads();
    }
    int excl = s[t] - v;
    if (t < NBKT) { bktbase[t] = excl; bktcur[t] = excl; }
    if (t == 255) { bktbase[NBKT] = s[255]; rowptr[N] = s[255]; }
}

// bin edges bucket-major; packed = (dst&511)<<23 | src  (src < 2^23)
__global__ void bin_edges(const int* __restrict__ src, const int* __restrict__ dst,
                          int* __restrict__ bktcur, unsigned* __restrict__ binned, int E) {
    __shared__ int hist[256];
    __shared__ int gbase[256];
    __shared__ int lcur[256];
    int t = threadIdx.x;
    hist[t] = 0;
    lcur[t] = 0;
    __syncthreads();
    int e0 = blockIdx.x * EPB;
#pragma unroll 4
    for (int k = 0; k < EPB / 256; ++k) {
        int e = e0 + k * 256 + t;
        if (e < E) atomicAdd(&hist[dst[e] >> 9], 1);
    }
    __syncthreads();
    if (hist[t] > 0) gbase[t] = atomicAdd(&bktcur[t], hist[t]);
    __syncthreads();
#pragma unroll 4
    for (int k = 0; k < EPB / 256; ++k) {
        int e = e0 + k * 256 + t;
        if (e < E) {
            int d = dst[e];
            int b = d >> 9;
            int r = atomicAdd(&lcur[b], 1);
            binned[gbase[b] + r] = ((unsigned)(d & 511) << 23) | (unsigned)src[e];
        }
    }
}

__global__ void bucket_build(const int* __restrict__ bktbase, const unsigned* __restrict__ binned,
                             int* __restrict__ rowptr, float* __restrict__ dinv,
                             int* __restrict__ csr_src, int N) {
    __shared__ int degl[512];
    __shared__ int s[512];
    __shared__ int rp[512];
    __shared__ int cur[512];
    int t = threadIdx.x;  // 512
    int n0 = blockIdx.x << 9;
    degl[t] = 0;
    cur[t] = 0;
    __syncthreads();
    int base = bktbase[blockIdx.x], end = bktbase[blockIdx.x + 1];
    for (int j = base + t; j < end; j += 512) atomicAdd(&degl[binned[j] >> 23], 1);
    __syncthreads();
    int d = degl[t];
    s[t] = d;
    __syncthreads();
    for (int off = 1; off < 512; off <<= 1) {
        int u = (t >= off) ? s[t - off] : 0;
        __syncthreads();
        s[t] += u;
        __syncthreads();
    }
    rp[t] = base + s[t] - d;  // exclusive
    int i = n0 + t;
    if (i < N) {
        rowptr[i] = rp[t];
        dinv[i] = rsqrtf((float)(d + 1));  // +1 self-loop
    }
    __syncthreads();
    for (int j = base + t; j < end; j += 512) {
        unsigned v = binned[j];
        int li = v >> 23;
        int slot = rp[li] + atomicAdd(&cur[li], 1);
        csr_src[slot] = (int)(v & 0x7FFFFFu);
    }
}

// ---- layer-1 GEMM: t1 = fp16( dinv[i] * (x[i] @ W1) )  [N,16] ------------
__global__ void gemm1(const float* __restrict__ x, const float* __restrict__ dinv,
                      const float* __restrict__ W, uint4* __restrict__ t1, int N) {
    __shared__ float Wl[128 * 16];
    int t = threadIdx.x;
    for (int k = t; k < 128 * 16; k += 256) Wl[k] = W[k];
    __syncthreads();
    int i = blockIdx.x * 256 + t;
    if (i >= N) return;
    const float4* x4 = (const float4*)(x + (size_t)i * 128);
    const float4* W4 = (const float4*)Wl;
    float4 a[4];
#pragma unroll
    for (int c = 0; c < 4; ++c) a[c] = make_float4(0.f, 0.f, 0.f, 0.f);
#pragma unroll 4
    for (int k4 = 0; k4 < 32; ++k4) {
        float4 v = x4[k4];
#pragma unroll
        for (int kk = 0; kk < 4; ++kk) {
            float xk = (kk == 0) ? v.x : (kk == 1) ? v.y : (kk == 2) ? v.z : v.w;
            const float4* Wr = W4 + (k4 * 4 + kk) * 4;
#pragma unroll
            for (int c = 0; c < 4; ++c) {
                float4 w = Wr[c];
                a[c].x += xk * w.x; a[c].y += xk * w.y;
                a[c].z += xk * w.z; a[c].w += xk * w.w;
            }
        }
    }
    float di = dinv[i];
    float f[16];
#pragma unroll
    for (int c = 0; c < 4; ++c) {
        f[4 * c + 0] = di * a[c].x; f[4 * c + 1] = di * a[c].y;
        f[4 * c + 2] = di * a[c].z; f[4 * c + 3] = di * a[c].w;
    }
    t1[(size_t)i * 2]     = f_to_h8(f);
    t1[(size_t)i * 2 + 1] = f_to_h8(f + 8);
}

// ---- gather over fp16 [N,16] rows (2 uint4 lanes per node) ---------------
// EPI: out = fp16( di*relu(di*g + b) ), else raw sums.
template <bool EPI>
__global__ void gather16(const int* __restrict__ rowptr, const int* __restrict__ csr_src,
                         const uint4* __restrict__ hs, const float* __restrict__ dinv,
                         const float* __restrict__ b, uint4* __restrict__ out, int N) {
    int tid = blockIdx.x * 256 + threadIdx.x;
    int i = tid >> 1, c = tid & 1;
    if (i >= N) return;
    float acc[8];
    h8_to_f(hs[(size_t)i * 2 + c], acc);  // self loop
    int j = rowptr[i], end = rowptr[i + 1];
    for (; j < end; ++j) {
        int s = csr_src[j];
        float v[8];
        h8_to_f(hs[(size_t)s * 2 + c], v);
#pragma unroll
        for (int k = 0; k < 8; ++k) acc[k] += v[k];
    }
    if (EPI) {
        float di = dinv[i];
#pragma unroll
        for (int k = 0; k < 8; ++k) acc[k] = di * fmaxf(di * acc[k] + b[c * 8 + k], 0.f);
    }
    out[(size_t)i * 2 + c] = f_to_h8(acc);
}

// ---- layer-2 GEMM: p2 = fp16( di*relu(di*(g2@W2)+b2) ), split cols -------
__global__ void gemm2(const uint4* __restrict__ g2, const float* __restrict__ dinv,
                      const float* __restrict__ W, const float* __restrict__ b,
                      uint4* __restrict__ p2a, uint4* __restrict__ p2b, int N) {
    __shared__ float Wl[16 * 32];
    __shared__ float bl[32];
    int t = threadIdx.x;
    for (int k = t; k < 16 * 32; k += 256) Wl[k] = W[k];
    if (t < 32) bl[t] = b[t];
    __syncthreads();
    int i = blockIdx.x * 256 + t;
    if (i >= N) return;
    float f[16];
    h8_to_f(g2[(size_t)i * 2], f);
    h8_to_f(g2[(size_t)i * 2 + 1], f + 8);
    const float4* W4 = (const float4*)Wl;
    float4 a[8];
#pragma unroll
    for (int c = 0; c < 8; ++c) a[c] = make_float4(0.f, 0.f, 0.f, 0.f);
#pragma unroll
    for (int k = 0; k < 16; ++k) {
        float xk = f[k];
        const float4* Wr = W4 + k * 8;
#pragma unroll
        for (int c = 0; c < 8; ++c) {
            float4 w = Wr[c];
            a[c].x += xk * w.x; a[c].y += xk * w.y;
            a[c].z += xk * w.z; a[c].w += xk * w.w;
        }
    }
    float di = dinv[i];
    float o[32];
#pragma unroll
    for (int c = 0; c < 8; ++c) {
        o[4 * c + 0] = di * fmaxf(di * a[c].x + bl[4 * c + 0], 0.f);
        o[4 * c + 1] = di * fmaxf(di * a[c].y + bl[4 * c + 1], 0.f);
        o[4 * c + 2] = di * fmaxf(di * a[c].z + bl[4 * c + 2], 0.f);
        o[4 * c + 3] = di * fmaxf(di * a[c].w + bl[4 * c + 3], 0.f);
    }
    p2a[(size_t)i * 2]     = f_to_h8(o);
    p2a[(size_t)i * 2 + 1] = f_to_h8(o + 8);
    p2b[(size_t)i * 2]     = f_to_h8(o + 16);
    p2b[(size_t)i * 2 + 1] = f_to_h8(o + 24);
}

// ---- layer-3 GEMM: h3 = fp16( relu(di*(g3@W3)+b3) )  [N,64] --------------
__global__ void gemm3(const uint4* __restrict__ g3a, const uint4* __restrict__ g3b,
                      const float* __restrict__ dinv, const float* __restrict__ W,
                      const float* __restrict__ b, uint4* __restrict__ h3, int N) {
    __shared__ float Wl[32 * 64];
    __shared__ float bl[64];
    int t = threadIdx.x;
    for (int k = t; k < 32 * 64; k += 256) Wl[k] = W[k];
    if (t < 64) bl[t] = b[t];
    __syncthreads();
    int i = blockIdx.x * 256 + t;
    if (i >= N) return;
    float f[32];
    h8_to_f(g3a[(size_t)i * 2], f);
    h8_to_f(g3a[(size_t)i * 2 + 1], f + 8);
    h8_to_f(g3b[(size_t)i * 2], f + 16);
    h8_to_f(g3b[(size_t)i * 2 + 1], f + 24);
    const float4* W4 = (const float4*)Wl;
    float4 a[16];
#pragma unroll
    for (int c = 0; c < 16; ++c) a[c] = make_float4(0.f, 0.f, 0.f, 0.f);
#pragma unroll 2
    for (int k = 0; k < 32; ++k) {
        float xk = f[k];
        const float4* Wr = W4 + k * 16;
#pragma unroll
        for (int c = 0; c < 16; ++c) {
            float4 w = Wr[c];
            a[c].x += xk * w.x; a[c].y += xk * w.y;
            a[c].z += xk * w.z; a[c].w += xk * w.w;
        }
    }
    float di = dinv[i];
    float o[64];
#pragma unroll
    for (int c = 0; c < 16; ++c) {
        o[4 * c + 0] = fmaxf(di * a[c].x + bl[4 * c + 0], 0.f);
        o[4 * c + 1] = fmaxf(di * a[c].y + bl[4 * c + 1], 0.f);
        o[4 * c + 2] = fmaxf(di * a[c].z + bl[4 * c + 2], 0.f);
        o[4 * c + 3] = fmaxf(di * a[c].w + bl[4 * c + 3], 0.f);
    }
#pragma unroll
    for (int q = 0; q < 8; ++q) h3[(size_t)i * 8 + q] = f_to_h8(o + 8 * q);
}

// ---- pool: batch sorted -> run-length max, one atomicMax per boundary ----
__global__ void finish_pool(const __half* __restrict__ h3, const int* __restrict__ batch,
                            unsigned* __restrict__ pooled, int N) {
    int f = threadIdx.x;  // 64
    int i0 = blockIdx.x * 64;
    int prevb = -1;
    float run = 0.f;
    for (int k = 0; k < 64; ++k) {
        int i = i0 + k;
        if (i >= N) break;
        int bg = batch[i];
        float v = __half2float(h3[(size_t)i * 64 + f]);
        if (bg != prevb) {
            if (prevb >= 0) atomicMax(&pooled[prevb * 64 + f], __float_as_uint(run));
            prevb = bg;
            run = v;
        } else {
            run = fmaxf(run, v);
        }
    }
    if (prevb >= 0) atomicMax(&pooled[prevb * 64 + f], __float_as_uint(run));
}

// ---- MLP head: one block (256 thr) per graph -----------------------------
__global__ void head(const float* __restrict__ pooled, const float* __restrict__ w1,
                     const float* __restrict__ bb1, const float* __restrict__ w2,
                     const float* __restrict__ bb2, float* __restrict__ out) {
    __shared__ float p[64];
    __shared__ float z[256];
    int g = blockIdx.x, t = threadIdx.x;
    if (t < 64) p[t] = pooled[g * 64 + t];
    __syncthreads();
    float s = bb1[t];
#pragma unroll
    for (int k = 0; k < 64; ++k) s += p[k] * w1[k * 256 + t];
    z[t] = fmaxf(s, 0.f);
    __syncthreads();
    float s2 = bb2[t];
#pragma unroll 8
    for (int k = 0; k < 256; ++k) s2 += z[k] * w2[k * 256 + t];
    out[g * 256 + t] = 1.f / (1.f + expf(-s2));
}

extern "C" void kernel_launch(void* const* d_in, const int* in_sizes, int n_in,
                              void* d_out, int out_size, void* d_ws, size_t ws_size,
                              hipStream_t stream) {
    const float* x   = (const float*)d_in[0];
    const int* ei    = (const int*)d_in[1];
    const int* batch = (const int*)d_in[2];
    const float* W1  = (const float*)d_in[3];
    const float* b1  = (const float*)d_in[4];
    const float* W2  = (const float*)d_in[5];
    const float* b2  = (const float*)d_in[6];
    const float* W3  = (const float*)d_in[7];
    const float* b3  = (const float*)d_in[8];
    const float* L1w = (const float*)d_in[9];
    const float* L1b = (const float*)d_in[10];
    const float* L2w = (const float*)d_in[11];
    const float* L2b = (const float*)d_in[12];

    const int N = in_sizes[0] / 128;
    const int E = in_sizes[1] / 2;
    const int* srcp = ei;
    const int* dstp = ei + E;
    const int NB = cdiv_i(N, 256);
    const int NBKT = cdiv_i(N, 512);  // <= 256

    // workspace carve, 16B-aligned chunks
    char* w = (char*)d_ws;
    auto carve = [&](size_t bytes) { char* p = w; w += (bytes + 15) & ~(size_t)15; return p; };
    int*   bcnt    = (int*)carve(256 * 4);
    int*   bktbase = (int*)carve(257 * 4);
    int*   bktcur  = (int*)carve(256 * 4);
    int*   rowptr  = (int*)carve((size_t)(N + 1) * 4);
    int*   csr_src = (int*)carve((size_t)E * 4);
    float* dinv    = (float*)carve((size_t)N * 4);
    uint4* t1      = (uint4*)carve((size_t)N * 32);   // [N,16] fp16
    uint4* p1      = (uint4*)carve((size_t)N * 32);
    uint4* g2      = (uint4*)carve((size_t)N * 32);
    uint4* p2a     = (uint4*)carve((size_t)N * 32);
    uint4* p2b     = (uint4*)carve((size_t)N * 32);
    uint4* g3a     = (uint4*)carve((size_t)N * 32);
    uint4* g3b     = (uint4*)carve((size_t)N * 32);
    uint4* h3      = (uint4*)carve((size_t)N * 128);  // [N,64] fp16; aliased as binned first
    unsigned* pooled = (unsigned*)carve((size_t)NG * 64 * 4);
    unsigned* binned = (unsigned*)h3;  // E*4 = 6.4MB <= N*128 = 12.8MB; dead before gemm3

    hipMemsetAsync(bcnt, 0, 256 * sizeof(int), stream);
    hipMemsetAsync(pooled, 0, (size_t)NG * 64 * sizeof(unsigned), stream);

    bucket_count<<<cdiv_i(E, EPB), 256, 0, stream>>>(dstp, bcnt, E);
    bucket_scan<<<1, 256, 0, stream>>>(bcnt, bktbase, bktcur, rowptr, NBKT, N);
    bin_edges<<<cdiv_i(E, EPB), 256, 0, stream>>>(srcp, dstp, bktcur, binned, E);
    bucket_build<<<NBKT, 512, 0, stream>>>(bktbase, binned, rowptr, dinv, csr_src, N);

    const int GG = cdiv_i((long long)N * 2, 256);  // gather grid

    // Layer 1: t1 = fp16(dinv*(x@W1)); p1 = fp16(di*relu(di*gather(t1)+b1))
    gemm1<<<NB, 256, 0, stream>>>(x, dinv, W1, t1, N);
    gather16<true><<<GG, 256, 0, stream>>>(rowptr, csr_src, t1, dinv, b1, p1, N);

    // Layer 2 (aggregate-first): g2 = gather(p1); p2 = fp16 split
    gather16<false><<<GG, 256, 0, stream>>>(rowptr, csr_src, p1, nullptr, nullptr, g2, N);
    gemm2<<<NB, 256, 0, stream>>>(g2, dinv, W2, b2, p2a, p2b, N);

    // Layer 3 (aggregate-first, column-split): g3{a,b} = gather(p2{a,b})
    gather16<false><<<GG, 256, 0, stream>>>(rowptr, csr_src, p2a, nullptr, nullptr, g3a, N);
    gather16<false><<<GG, 256, 0, stream>>>(rowptr, csr_src, p2b, nullptr, nullptr, g3b, N);
    gemm3<<<NB, 256, 0, stream>>>(g3a, g3b, dinv, W3, b3, h3, N);

    // pool + head
    finish_pool<<<cdiv_i(N, 64), 64, 0, stream>>>((const __half*)h3, batch, pooled, N);
    head<<<NG, 256, 0, stream>>>((const float*)pooled, L1w, L1b, L2w, L2b, (float*)d_out);
}

// Round 7
// 216.952 us; speedup vs baseline: 11.4262x; 1.2011x over previous
//
#include <hip/hip_runtime.h>
#include <hip/hip_fp16.h>
#include <math.h>

#define NG 1024   // NUM_GRAPHS
#define EPB 8192  // edges per binning block

static inline int cdiv_i(long long a, int b) { return (int)((a + b - 1) / b); }

// ---- fp16 pack/unpack helpers (8 halves per uint4) -----------------------
union H8 { uint4 u; __half2 h[4]; };

__device__ inline void h8_to_f(uint4 uu, float* f) {
    H8 v; v.u = uu;
#pragma unroll
    for (int k = 0; k < 4; ++k) {
        float2 t = __half22float2(v.h[k]);
        f[2 * k] = t.x; f[2 * k + 1] = t.y;
    }
}
__device__ inline uint4 f_to_h8(const float* f) {
    H8 v;
#pragma unroll
    for (int k = 0; k < 4; ++k) v.h[k] = __floats2half2_rn(f[2 * k], f[2 * k + 1]);
    return v.u;
}

// ---- CSR build (bucketed, no per-node global atomics) --------------------
// bucket b = nodes [b*512, (b+1)*512)

__global__ void bucket_count(const int* __restrict__ dst, int* __restrict__ bcnt, int E) {
    __shared__ int h[256];
    int t = threadIdx.x;
    h[t] = 0;
    __syncthreads();
    int e0 = blockIdx.x * EPB;
#pragma unroll 4
    for (int k = 0; k < EPB / 256; ++k) {
        int e = e0 + k * 256 + t;
        if (e < E) atomicAdd(&h[dst[e] >> 9], 1);
    }
    __syncthreads();
    if (h[t] > 0) atomicAdd(&bcnt[t], h[t]);
}

__global__ void bucket_scan(const int* __restrict__ bcnt, int* __restrict__ bktbase,
                            int* __restrict__ bktcur, int* __restrict__ rowptr,
                            int NBKT, int N) {
    __shared__ int s[256];
    int t = threadIdx.x;
    int v = (t < NBKT) ? bcnt[t] : 0;
    s[t] = v;
    __syncthreads();
    for (int off = 1; off < 256; off <<= 1) {
        int u = (t >= off) ? s[t - off] : 0;
        __syncthreads();
        s[t] += u;
        __syncthreads();
    }
    int excl = s[t] - v;
    if (t < NBKT) { bktbase[t] = excl; bktcur[t] = excl; }
    if (t == 255) { bktbase[NBKT] = s[255]; rowptr[N] = s[255]; }
}

// bin edges bucket-major; packed = (dst&511)<<23 | src  (src < 2^23)
__global__ void bin_edges(const int* __restrict__ src, const int* __restrict__ dst,
                          int* __restrict__ bktcur, unsigned* __restrict__ binned, int E) {
    __shared__ int hist[256];
    __shared__ int gbase[256];
    __shared__ int lcur[256];
    int t = threadIdx.x;
    hist[t] = 0;
    lcur[t] = 0;
    __syncthreads();
    int e0 = blockIdx.x * EPB;
#pragma unroll 4
    for (int k = 0; k < EPB / 256; ++k) {
        int e = e0 + k * 256 + t;
        if (e < E) atomicAdd(&hist[dst[e] >> 9], 1);
    }
    __syncthreads();
    if (hist[t] > 0) gbase[t] = atomicAdd(&bktcur[t], hist[t]);
    __syncthreads();
#pragma unroll 4
    for (int k = 0; k < EPB / 256; ++k) {
        int e = e0 + k * 256 + t;
        if (e < E) {
            int d = dst[e];
            int b = d >> 9;
            int r = atomicAdd(&lcur[b], 1);
            binned[gbase[b] + r] = ((unsigned)(d & 511) << 23) | (unsigned)src[e];
        }
    }
}

__global__ void bucket_build(const int* __restrict__ bktbase, const unsigned* __restrict__ binned,
                             int* __restrict__ rowptr, float* __restrict__ dinv,
                             int* __restrict__ csr_src, int N) {
    __shared__ int degl[512];
    __shared__ int s[512];
    __shared__ int rp[512];
    __shared__ int cur[512];
    int t = threadIdx.x;  // 512
    int n0 = blockIdx.x << 9;
    degl[t] = 0;
    cur[t] = 0;
    __syncthreads();
    int base = bktbase[blockIdx.x], end = bktbase[blockIdx.x + 1];
    for (int j = base + t; j < end; j += 512) atomicAdd(&degl[binned[j] >> 23], 1);
    __syncthreads();
    int d = degl[t];
    s[t] = d;
    __syncthreads();
    for (int off = 1; off < 512; off <<= 1) {
        int u = (t >= off) ? s[t - off] : 0;
        __syncthreads();
        s[t] += u;
        __syncthreads();
    }
    rp[t] = base + s[t] - d;  // exclusive
    int i = n0 + t;
    if (i < N) {
        rowptr[i] = rp[t];
        dinv[i] = rsqrtf((float)(d + 1));  // +1 self-loop
    }
    __syncthreads();
    for (int j = base + t; j < end; j += 512) {
        unsigned v = binned[j];
        int li = v >> 23;
        int slot = rp[li] + atomicAdd(&cur[li], 1);
        csr_src[slot] = (int)(v & 0x7FFFFFu);
    }
}

// ---- layer-1 GEMM: t1 = fp16( dinv[i] * (x[i] @ W1) )  [N,16] ------------
__global__ void gemm1(const float* __restrict__ x, const float* __restrict__ dinv,
                      const float* __restrict__ W, uint4* __restrict__ t1, int N) {
    __shared__ float Wl[128 * 16];
    int t = threadIdx.x;
    for (int k = t; k < 128 * 16; k += 256) Wl[k] = W[k];
    __syncthreads();
    int i = blockIdx.x * 256 + t;
    if (i >= N) return;
    const float4* x4 = (const float4*)(x + (size_t)i * 128);
    const float4* W4 = (const float4*)Wl;
    float4 a[4];
#pragma unroll
    for (int c = 0; c < 4; ++c) a[c] = make_float4(0.f, 0.f, 0.f, 0.f);
#pragma unroll 4
    for (int k4 = 0; k4 < 32; ++k4) {
        float4 v = x4[k4];
#pragma unroll
        for (int kk = 0; kk < 4; ++kk) {
            float xk = (kk == 0) ? v.x : (kk == 1) ? v.y : (kk == 2) ? v.z : v.w;
            const float4* Wr = W4 + (k4 * 4 + kk) * 4;
#pragma unroll
            for (int c = 0; c < 4; ++c) {
                float4 w = Wr[c];
                a[c].x += xk * w.x; a[c].y += xk * w.y;
                a[c].z += xk * w.z; a[c].w += xk * w.w;
            }
        }
    }
    float di = dinv[i];
    float f[16];
#pragma unroll
    for (int c = 0; c < 4; ++c) {
        f[4 * c + 0] = di * a[c].x; f[4 * c + 1] = di * a[c].y;
        f[4 * c + 2] = di * a[c].z; f[4 * c + 3] = di * a[c].w;
    }
    t1[(size_t)i * 2]     = f_to_h8(f);
    t1[(size_t)i * 2 + 1] = f_to_h8(f + 8);
}

// ---- gather over fp16 [N,16] rows (2 uint4 lanes per node) ---------------
// EPI: out = fp16( di*relu(di*g + b) ), else raw sums.
template <bool EPI>
__global__ void gather16(const int* __restrict__ rowptr, const int* __restrict__ csr_src,
                         const uint4* __restrict__ hs, const float* __restrict__ dinv,
                         const float* __restrict__ b, uint4* __restrict__ out, int N) {
    int tid = blockIdx.x * 256 + threadIdx.x;
    int i = tid >> 1, c = tid & 1;
    if (i >= N) return;
    float acc[8];
    h8_to_f(hs[(size_t)i * 2 + c], acc);  // self loop
    int j = rowptr[i], end = rowptr[i + 1];
    for (; j < end; ++j) {
        int s = csr_src[j];
        float v[8];
        h8_to_f(hs[(size_t)s * 2 + c], v);
#pragma unroll
        for (int k = 0; k < 8; ++k) acc[k] += v[k];
    }
    if (EPI) {
        float di = dinv[i];
#pragma unroll
        for (int k = 0; k < 8; ++k) acc[k] = di * fmaxf(di * acc[k] + b[c * 8 + k], 0.f);
    }
    out[(size_t)i * 2 + c] = f_to_h8(acc);
}

// ---- layer-2 GEMM: p2 = fp16( di*relu(di*(g2@W2)+b2) ), split cols -------
__global__ void gemm2(const uint4* __restrict__ g2, const float* __restrict__ dinv,
                      const float* __restrict__ W, const float* __restrict__ b,
                      uint4* __restrict__ p2a, uint4* __restrict__ p2b, int N) {
    __shared__ float Wl[16 * 32];
    __shared__ float bl[32];
    int t = threadIdx.x;
    for (int k = t; k < 16 * 32; k += 256) Wl[k] = W[k];
    if (t < 32) bl[t] = b[t];
    __syncthreads();
    int i = blockIdx.x * 256 + t;
    if (i >= N) return;
    float f[16];
    h8_to_f(g2[(size_t)i * 2], f);
    h8_to_f(g2[(size_t)i * 2 + 1], f + 8);
    const float4* W4 = (const float4*)Wl;
    float4 a[8];
#pragma unroll
    for (int c = 0; c < 8; ++c) a[c] = make_float4(0.f, 0.f, 0.f, 0.f);
#pragma unroll
    for (int k = 0; k < 16; ++k) {
        float xk = f[k];
        const float4* Wr = W4 + k * 8;
#pragma unroll
        for (int c = 0; c < 8; ++c) {
            float4 w = Wr[c];
            a[c].x += xk * w.x; a[c].y += xk * w.y;
            a[c].z += xk * w.z; a[c].w += xk * w.w;
        }
    }
    float di = dinv[i];
    float o[32];
#pragma unroll
    for (int c = 0; c < 8; ++c) {
        o[4 * c + 0] = di * fmaxf(di * a[c].x + bl[4 * c + 0], 0.f);
        o[4 * c + 1] = di * fmaxf(di * a[c].y + bl[4 * c + 1], 0.f);
        o[4 * c + 2] = di * fmaxf(di * a[c].z + bl[4 * c + 2], 0.f);
        o[4 * c + 3] = di * fmaxf(di * a[c].w + bl[4 * c + 3], 0.f);
    }
    p2a[(size_t)i * 2]     = f_to_h8(o);
    p2a[(size_t)i * 2 + 1] = f_to_h8(o + 8);
    p2b[(size_t)i * 2]     = f_to_h8(o + 16);
    p2b[(size_t)i * 2 + 1] = f_to_h8(o + 24);
}

// ---- layer-3 GEMM fused with segment-max pool ----------------------------
// 256 threads = 128 nodes x 2 col-halves (c = t>>7, wave-uniform).
// Each thread: 32 input feats, 32 output cols (a[8] float4, no spill).
// Outputs staged in LDS [128][65] (pad -> conflict-free), then 4 strips x 64
// feats run-length max over sorted batch, one atomicMax per boundary.
__global__ void gemm3_pool(const uint4* __restrict__ g3a, const uint4* __restrict__ g3b,
                           const float* __restrict__ dinv, const float* __restrict__ W,
                           const float* __restrict__ b, const int* __restrict__ batch,
                           unsigned* __restrict__ pooled, int N) {
    __shared__ float Wl[32 * 64];
    __shared__ float bl[64];
    __shared__ float pl[128][65];
    __shared__ int bt[128];
    int t = threadIdx.x;
    for (int k = t; k < 32 * 64; k += 256) Wl[k] = W[k];
    if (t < 64) bl[t] = b[t];
    int i0 = blockIdx.x * 128;
    if (t < 128) {
        int i = i0 + t;
        bt[t] = (i < N) ? batch[i] : -1;
    }
    __syncthreads();
    int il = t & 127, c = t >> 7;  // node-local, col-half (wave-uniform)
    int i = i0 + il;
    if (i < N) {
        float f[32];
        h8_to_f(g3a[(size_t)i * 2], f);
        h8_to_f(g3a[(size_t)i * 2 + 1], f + 8);
        h8_to_f(g3b[(size_t)i * 2], f + 16);
        h8_to_f(g3b[(size_t)i * 2 + 1], f + 24);
        const float4* W4 = (const float4*)Wl;
        float4 a[8];
#pragma unroll
        for (int cc = 0; cc < 8; ++cc) a[cc] = make_float4(0.f, 0.f, 0.f, 0.f);
#pragma unroll 4
        for (int k = 0; k < 32; ++k) {
            float xk = f[k];
            const float4* Wr = W4 + k * 16 + c * 8;
#pragma unroll
            for (int cc = 0; cc < 8; ++cc) {
                float4 w = Wr[cc];
                a[cc].x += xk * w.x; a[cc].y += xk * w.y;
                a[cc].z += xk * w.z; a[cc].w += xk * w.w;
            }
        }
        float di = dinv[i];
        int fb = c * 32;
#pragma unroll
        for (int cc = 0; cc < 8; ++cc) {
            pl[il][fb + 4 * cc + 0] = fmaxf(di * a[cc].x + bl[fb + 4 * cc + 0], 0.f);
            pl[il][fb + 4 * cc + 1] = fmaxf(di * a[cc].y + bl[fb + 4 * cc + 1], 0.f);
            pl[il][fb + 4 * cc + 2] = fmaxf(di * a[cc].z + bl[fb + 4 * cc + 2], 0.f);
            pl[il][fb + 4 * cc + 3] = fmaxf(di * a[cc].w + bl[fb + 4 * cc + 3], 0.f);
        }
    }
    __syncthreads();
    // pool: 4 strips of 32 nodes, 64 features each
    int f = t & 63, q = t >> 6;
    int prevb = -1;
    float run = 0.f;
    for (int k = 0; k < 32; ++k) {
        int il2 = q * 32 + k;
        int bg = bt[il2];
        if (bg < 0) break;  // past N (batch sorted, tail only in last block)
        float v = pl[il2][f];
        if (bg != prevb) {
            if (prevb >= 0) atomicMax(&pooled[prevb * 64 + f], __float_as_uint(run));
            prevb = bg;
            run = v;
        } else {
            run = fmaxf(run, v);
        }
    }
    if (prevb >= 0) atomicMax(&pooled[prevb * 64 + f], __float_as_uint(run));
}

// ---- MLP head: one block (256 thr) per graph -----------------------------
__global__ void head(const float* __restrict__ pooled, const float* __restrict__ w1,
                     const float* __restrict__ bb1, const float* __restrict__ w2,
                     const float* __restrict__ bb2, float* __restrict__ out) {
    __shared__ float p[64];
    __shared__ float z[256];
    int g = blockIdx.x, t = threadIdx.x;
    if (t < 64) p[t] = pooled[g * 64 + t];
    __syncthreads();
    float s = bb1[t];
#pragma unroll
    for (int k = 0; k < 64; ++k) s += p[k] * w1[k * 256 + t];
    z[t] = fmaxf(s, 0.f);
    __syncthreads();
    float s2 = bb2[t];
#pragma unroll 8
    for (int k = 0; k < 256; ++k) s2 += z[k] * w2[k * 256 + t];
    out[g * 256 + t] = 1.f / (1.f + expf(-s2));
}

extern "C" void kernel_launch(void* const* d_in, const int* in_sizes, int n_in,
                              void* d_out, int out_size, void* d_ws, size_t ws_size,
                              hipStream_t stream) {
    const float* x   = (const float*)d_in[0];
    const int* ei    = (const int*)d_in[1];
    const int* batch = (const int*)d_in[2];
    const float* W1  = (const float*)d_in[3];
    const float* b1  = (const float*)d_in[4];
    const float* W2  = (const float*)d_in[5];
    const float* b2  = (const float*)d_in[6];
    const float* W3  = (const float*)d_in[7];
    const float* b3  = (const float*)d_in[8];
    const float* L1w = (const float*)d_in[9];
    const float* L1b = (const float*)d_in[10];
    const float* L2w = (const float*)d_in[11];
    const float* L2b = (const float*)d_in[12];

    const int N = in_sizes[0] / 128;
    const int E = in_sizes[1] / 2;
    const int* srcp = ei;
    const int* dstp = ei + E;
    const int NB = cdiv_i(N, 256);
    const int NBKT = cdiv_i(N, 512);  // <= 256

    // workspace carve, 16B-aligned chunks
    char* w = (char*)d_ws;
    auto carve = [&](size_t bytes) { char* p = w; w += (bytes + 15) & ~(size_t)15; return p; };
    int*   bcnt    = (int*)carve(256 * 4);
    int*   bktbase = (int*)carve(257 * 4);
    int*   bktcur  = (int*)carve(256 * 4);
    int*   rowptr  = (int*)carve((size_t)(N + 1) * 4);
    int*   csr_src = (int*)carve((size_t)E * 4);
    float* dinv    = (float*)carve((size_t)N * 4);
    uint4* t1      = (uint4*)carve((size_t)N * 32);   // [N,16] fp16
    uint4* p1      = (uint4*)carve((size_t)N * 32);
    uint4* g2      = (uint4*)carve((size_t)N * 32);
    uint4* p2a     = (uint4*)carve((size_t)N * 32);
    uint4* p2b     = (uint4*)carve((size_t)N * 32);
    uint4* g3a     = (uint4*)carve((size_t)N * 32);
    uint4* g3b     = (uint4*)carve((size_t)N * 32);
    unsigned* binned = (unsigned*)carve((size_t)E * 4);
    unsigned* pooled = (unsigned*)carve((size_t)NG * 64 * 4);

    hipMemsetAsync(bcnt, 0, 256 * sizeof(int), stream);
    hipMemsetAsync(pooled, 0, (size_t)NG * 64 * sizeof(unsigned), stream);

    bucket_count<<<cdiv_i(E, EPB), 256, 0, stream>>>(dstp, bcnt, E);
    bucket_scan<<<1, 256, 0, stream>>>(bcnt, bktbase, bktcur, rowptr, NBKT, N);
    bin_edges<<<cdiv_i(E, EPB), 256, 0, stream>>>(srcp, dstp, bktcur, binned, E);
    bucket_build<<<NBKT, 512, 0, stream>>>(bktbase, binned, rowptr, dinv, csr_src, N);

    const int GG = cdiv_i((long long)N * 2, 256);  // gather grid

    // Layer 1: t1 = fp16(dinv*(x@W1)); p1 = fp16(di*relu(di*gather(t1)+b1))
    gemm1<<<NB, 256, 0, stream>>>(x, dinv, W1, t1, N);
    gather16<true><<<GG, 256, 0, stream>>>(rowptr, csr_src, t1, dinv, b1, p1, N);

    // Layer 2 (aggregate-first): g2 = gather(p1); p2 = fp16 split
    gather16<false><<<GG, 256, 0, stream>>>(rowptr, csr_src, p1, nullptr, nullptr, g2, N);
    gemm2<<<NB, 256, 0, stream>>>(g2, dinv, W2, b2, p2a, p2b, N);

    // Layer 3 (aggregate-first, column-split): g3{a,b} = gather(p2{a,b})
    gather16<false><<<GG, 256, 0, stream>>>(rowptr, csr_src, p2a, nullptr, nullptr, g3a, N);
    gather16<false><<<GG, 256, 0, stream>>>(rowptr, csr_src, p2b, nullptr, nullptr, g3b, N);
    // gemm3 + relu + segment-max pool fused (h3 never materialized)
    gemm3_pool<<<cdiv_i(N, 128), 256, 0, stream>>>(g3a, g3b, dinv, W3, b3, batch, pooled, N);

    // head
    head<<<NG, 256, 0, stream>>>((const float*)pooled, L1w, L1b, L2w, L2b, (float*)d_out);
}